// Round 11
// baseline (499.297 us; speedup 1.0000x reference)
//
#include <hip/hip_runtime.h>
#include <cfloat>
#include <cmath>

// ---------------------------------------------------------------------------
// GNN message passing — fp16 MFMA, round 11.
//  R11 changes (theory-first; r10 evidence: k_binB 71us latency-bound at 14.7%
//  occupancy with dependent random ew reads; k_mlp 70us half-VALU/half-latency):
//   1. binA packs ew as 4xfp16 INTO staged (int4; ew4[e] read is coalesced in
//      binA). binB loses all random reads; stats use int atomics on fp16 bit
//      patterns (monotone => max/min EXACT vs prior fp32 path) + fp32 sum of
//      fp16-rounded values (error << the fp16 quantization already applied on
//      store). binB threads 512 -> 1024 (16 waves/CU).
//   2. k_mlp gather stride 16 -> 32 edges/iter (8 rows in flight per lane):
//      2x memory-level parallelism. Clamped duplicate loads in quad B hit one
//      row (TA-merged) and are idempotent (max/min) / masked (sum).
//  WRITE_SIZE is the spill sentinel for (2): must stay ~6250 KB.
// MFMA mapping (verified r3-r10): D=A*B, A=W^T[nout][k], B=H[node][k]; D:
// col=lane&15=node, row=(lane>>4)*4+reg=nout.
// ---------------------------------------------------------------------------

typedef _Float16 half_t;
typedef _Float16 half8 __attribute__((ext_vector_type(8)));
typedef _Float16 half4_t __attribute__((ext_vector_type(4)));
typedef _Float16 half2_t __attribute__((ext_vector_type(2)));
typedef float f32x4 __attribute__((ext_vector_type(4)));

#define NPB 512       // nodes per bin (power of 2: bin = dst>>9)
#define BIN_CAP 9216  // slots per bin; mean 8163, sd ~90 -> +11.7 sigma
#define IDXCAP 4352   // LDS idx slots per k_mlp block (mean 1024)

__device__ __forceinline__ float fast_tanh(float x) {
    float e = __builtin_amdgcn_exp2f(x * 2.8853900817779268f);
    return 1.0f - 2.0f * __builtin_amdgcn_rcpf(1.0f + e);
}

__device__ __forceinline__ half_t cvt_clamp(float v) {
    return (half_t)fminf(fmaxf(v, -60000.f), 60000.f);
}

__device__ __forceinline__ half2_t h2shfl_xor(half2_t v, int mask) {
    int i = __builtin_bit_cast(int, v);
    i = __shfl_xor(i, mask);
    return __builtin_bit_cast(half2_t, i);
}

// ---------------- phase A: bin edges + pack fp16 ew (coalesced staging) ----------------
__global__ __launch_bounds__(256) void k_binA(
    const int* __restrict__ dst, const int* __restrict__ src,
    const float4* __restrict__ ew4,
    int* __restrict__ binCnt, int4* __restrict__ staged, int E, int nbins) {
    __shared__ int cnt[256], base[256], cur[256];
    int t = threadIdx.x;
    cnt[t] = 0;
    cur[t] = 0;
    __syncthreads();
    int e0 = blockIdx.x * 8192;
#pragma unroll 4
    for (int i = 0; i < 32; ++i) {
        int e = e0 + i * 256 + t;
        if (e < E) atomicAdd(&cnt[dst[e] >> 9], 1);
    }
    __syncthreads();
    if (t < nbins && cnt[t] > 0) base[t] = atomicAdd(&binCnt[t], cnt[t]);
    __syncthreads();
#pragma unroll 4
    for (int i = 0; i < 32; ++i) {
        int e = e0 + i * 256 + t;
        if (e < E) {
            int d = dst[e];
            int b = d >> 9;
            int j = base[b] + atomicAdd(&cur[b], 1);
            if (j < BIN_CAP) {
                float4 w = ew4[e];   // coalesced here (e sequential)
                half2_t lo = {(half_t)w.x, (half_t)w.y};
                half2_t hi = {(half_t)w.z, (half_t)w.w};
                staged[(size_t)b * BIN_CAP + j] =
                    make_int4(src[e], d & (NPB - 1),
                              __builtin_bit_cast(int, lo),
                              __builtin_bit_cast(int, hi));
            }
        }
    }
}

// ---------------- bin-count exclusive scan (nbins <= 256) ----------------
__global__ void k_scanN(const int* __restrict__ binCnt, int* __restrict__ binStart,
                        int* __restrict__ row_start, int nbins, int n, int E) {
    __shared__ int sh[256];
    int t = threadIdx.x;
    int v = (t < nbins) ? binCnt[t] : 0;
    sh[t] = v;
    __syncthreads();
    for (int s = 1; s < 256; s <<= 1) {
        int u = (t >= s) ? sh[t - s] : 0;
        __syncthreads();
        sh[t] += u;
        __syncthreads();
    }
    if (t < nbins) binStart[t] = sh[t] - v;
    if (t == 0) row_start[n] = E;
}

// ---------------- phase B: per-bin CSR + stats (all from staged) + reps ----------------
__global__ __launch_bounds__(1024) void k_binB(
    const int* __restrict__ binCnt, const int* __restrict__ binStart,
    const int4* __restrict__ staged, const float* __restrict__ x,
    int* __restrict__ row_start, int* __restrict__ snbr,
    half_t* __restrict__ reps, int n) {
    __shared__ int deg[NPB], cur[NPB], rsl[NPB];
    __shared__ float ssum[NPB * 4];
    __shared__ int smax[NPB * 4], smin[NPB * 4];   // fp16 bits (ew >= 0)
    int t = threadIdx.x;
    int bin = blockIdx.x;
    int cntE = min(binCnt[bin], BIN_CAP);
    int pbase = binStart[bin];
    const int4* st = staged + (size_t)bin * BIN_CAP;

    if (t < NPB) { deg[t] = 0; cur[t] = 0; }
    for (int i = t; i < NPB * 4; i += 1024) {
        ssum[i] = 0.f;
        smax[i] = 0;         // fp16 +0 (ew >= 0 lower bound)
        smin[i] = 0x7BFF;    // fp16 65504 bits
    }
    __syncthreads();

    // pass 1: degree count + stats (coalesced staged reads, no random loads)
    for (int i = t; i < cntE; i += 1024) {
        int4 v = st[i];
        int dl = v.y;
        atomicAdd(&deg[dl], 1);
        int b0 = v.z & 0xFFFF, b1 = (v.z >> 16) & 0xFFFF;
        int b2 = v.w & 0xFFFF, b3 = (v.w >> 16) & 0xFFFF;
        half2_t lo = __builtin_bit_cast(half2_t, v.z);
        half2_t hi = __builtin_bit_cast(half2_t, v.w);
        atomicAdd(&ssum[dl * 4 + 0], (float)lo[0]);
        atomicAdd(&ssum[dl * 4 + 1], (float)lo[1]);
        atomicAdd(&ssum[dl * 4 + 2], (float)hi[0]);
        atomicAdd(&ssum[dl * 4 + 3], (float)hi[1]);
        atomicMax(&smax[dl * 4 + 0], b0);
        atomicMax(&smax[dl * 4 + 1], b1);
        atomicMax(&smax[dl * 4 + 2], b2);
        atomicMax(&smax[dl * 4 + 3], b3);
        atomicMin(&smin[dl * 4 + 0], b0);
        atomicMin(&smin[dl * 4 + 1], b1);
        atomicMin(&smin[dl * 4 + 2], b2);
        atomicMin(&smin[dl * 4 + 3], b3);
    }
    __syncthreads();

    int own = (t < NPB) ? deg[t] : 0;
    for (int s = 1; s < NPB; s <<= 1) {   // inclusive Hillis-Steele (t<512 active)
        int u = (t < NPB && t >= s) ? deg[t - s] : 0;
        __syncthreads();
        if (t < NPB) deg[t] += u;
        __syncthreads();
    }
    int node = bin * NPB + t;
    if (t < NPB) {
        int excl = deg[t] - own;
        rsl[t] = pbase + excl;
        if (node < n) row_start[node] = pbase + excl;
    }
    __syncthreads();

    // scatter pass: snbr only
    for (int i = t; i < cntE; i += 1024) {
        int4 v = st[i];
        int p = rsl[v.y] + atomicAdd(&cur[v.y], 1);
        snbr[p] = v.x;
    }

    // reps row: [x(8), mean(4), max(4), min(4), sum(4), 0(8)] in fp16
    if (t < NPB && node < n) {
        float cnt = fmaxf((float)own, 1.0f);
        float rc = __builtin_amdgcn_rcpf(cnt);
        float sm0 = ssum[t * 4 + 0], sm1 = ssum[t * 4 + 1];
        float sm2 = ssum[t * 4 + 2], sm3 = ssum[t * 4 + 3];
        float mx0, mx1, mx2, mx3, mn0, mn1, mn2, mn3;
        if (own == 0) {
            mx0 = mx1 = mx2 = mx3 = -FLT_MAX;
            mn0 = mn1 = mn2 = mn3 = FLT_MAX;
        } else {
            mx0 = (float)__builtin_bit_cast(half_t, (unsigned short)smax[t * 4 + 0]);
            mx1 = (float)__builtin_bit_cast(half_t, (unsigned short)smax[t * 4 + 1]);
            mx2 = (float)__builtin_bit_cast(half_t, (unsigned short)smax[t * 4 + 2]);
            mx3 = (float)__builtin_bit_cast(half_t, (unsigned short)smax[t * 4 + 3]);
            mn0 = (float)__builtin_bit_cast(half_t, (unsigned short)smin[t * 4 + 0]);
            mn1 = (float)__builtin_bit_cast(half_t, (unsigned short)smin[t * 4 + 1]);
            mn2 = (float)__builtin_bit_cast(half_t, (unsigned short)smin[t * 4 + 2]);
            mn3 = (float)__builtin_bit_cast(half_t, (unsigned short)smin[t * 4 + 3]);
        }
        const float4* x4 = reinterpret_cast<const float4*>(x);
        float4 x0 = x4[node * 2 + 0], x1 = x4[node * 2 + 1];
        half_t* o = &reps[(size_t)node * 32];
        half8 c0 = {cvt_clamp(x0.x), cvt_clamp(x0.y), cvt_clamp(x0.z), cvt_clamp(x0.w),
                    cvt_clamp(x1.x), cvt_clamp(x1.y), cvt_clamp(x1.z), cvt_clamp(x1.w)};
        half8 c1 = {cvt_clamp(sm0 * rc), cvt_clamp(sm1 * rc), cvt_clamp(sm2 * rc), cvt_clamp(sm3 * rc),
                    cvt_clamp(mx0), cvt_clamp(mx1), cvt_clamp(mx2), cvt_clamp(mx3)};
        half8 c2 = {cvt_clamp(mn0), cvt_clamp(mn1), cvt_clamp(mn2), cvt_clamp(mn3),
                    cvt_clamp(sm0), cvt_clamp(sm1), cvt_clamp(sm2), cvt_clamp(sm3)};
        half8 c3 = {(half_t)0.f, (half_t)0.f, (half_t)0.f, (half_t)0.f,
                    (half_t)0.f, (half_t)0.f, (half_t)0.f, (half_t)0.f};
        *(half8*)&o[0] = c0;
        *(half8*)&o[8] = c1;
        *(half8*)&o[16] = c2;
        *(half8*)&o[24] = c3;
    }
}

// ---------------- weight prep: fp32 [k][n] -> fp16 [n][k] ----------------
__global__ void k_wprep(const float* __restrict__ Wu1, const float* __restrict__ Wu2,
                        const float* __restrict__ Wu3, half_t* __restrict__ Wt1,
                        half_t* __restrict__ Wt2, half_t* __restrict__ Wt3) {
    int i = blockIdx.x * 256 + threadIdx.x;
    if (i < 32768) {
        int nrow = i >> 7, k = i & 127;
        Wt1[i] = (half_t)Wu1[k * 256 + nrow];
    } else if (i < 65536) {
        int j = i - 32768;
        int nrow = j >> 8, k = j & 255;
        Wt2[j] = (half_t)Wu2[k * 128 + nrow];
    } else if (i < 69632) {
        int j = i - 65536;
        int nrow = j >> 7, k = j & 127;
        Wt3[j] = (half_t)Wu3[k * 32 + nrow];
    }
}

// ---------------- fused iter: LDS-idx gather + split-K MFMA MLP + l2norm ----------------
#define MFMA16(a, b, c) __builtin_amdgcn_mfma_f32_16x16x32_f16((a), (b), (c), 0, 0, 0)

__global__ __launch_bounds__(512, 6) void k_mlp(
    const half_t* __restrict__ reps_in,
    const int* __restrict__ row_start, const int* __restrict__ snbr,
    const half_t* __restrict__ Wt1, const half_t* __restrict__ Wt2,
    const half_t* __restrict__ Wt3,
    const float* __restrict__ bu1, const float* __restrict__ bu2,
    const float* __restrict__ bu3,
    half_t* __restrict__ reps_out, int n) {
    __shared__ half_t sH[64 * 136];     // H[64][128]; later h2[64][128]
    __shared__ half_t sh1c[64 * 136];   // idx stage, then h1 chunk [64][128]
    int* sIdx = (int*)sh1c;             // 4352 int slots

    const int tid = threadIdx.x;
    const int w   = tid >> 6;
    const int l15 = tid & 15;
    const int lk  = (tid & 63) >> 4;
    const int node0 = blockIdx.x * 64;

    // ---- idx stage: block's CSR range is contiguous -> coalesced LDS burst ----
    const int nodeEnd = min(node0 + 64, n);
    const int d0blk = row_start[node0];
    const int ecnt = row_start[nodeEnd] - d0blk;
    const bool lds_ok = (ecnt <= IDXCAP);
    if (lds_ok) {
        for (int i = tid; i < ecnt; i += 512)
            sIdx[i] = __builtin_nontemporal_load(&snbr[d0blk + i]);
    }
    __syncthreads();

    // ---- gather: 32 subgroups of 16 lanes; lane=(nb,ch); 32 edges/iter ----
    // 8 rows in flight per lane. Quad-B clamped duplicates: same-row loads
    // (TA-merged), idempotent for max/min, masked out for sum.
    {
        const int sg = tid >> 4;
        const int l  = tid & 15;
        const int nb = l >> 2;
        const int ch = l & 3;

        for (int i = 0; i < 2; ++i) {
            int nl = i * 32 + sg;
            int node = node0 + nl;
            float s[8];
            half2_t mx2[4], mn2[4];
#pragma unroll
            for (int f = 0; f < 8; ++f) s[f] = 0.f;
#pragma unroll
            for (int f = 0; f < 4; ++f) {
                mx2[f] = (half2_t){(half_t)-65504.f, (half_t)-65504.f};
                mn2[f] = (half2_t){(half_t)65504.f, (half_t)65504.f};
            }
            int d0 = 0, d1 = 0;
            if (node < n) { d0 = row_start[node]; d1 = row_start[node + 1]; }

            for (int e = d0; e < d1; e += 32) {
                int eA0 = e + nb,      eA1 = e + 4 + nb;
                int eA2 = e + 8 + nb,  eA3 = e + 12 + nb;
                int eB0 = e + 16 + nb, eB1 = e + 20 + nb;
                int eB2 = e + 24 + nb, eB3 = e + 28 + nb;
                float mA0 = (eA0 < d1) ? 1.f : 0.f, mA1 = (eA1 < d1) ? 1.f : 0.f;
                float mA2 = (eA2 < d1) ? 1.f : 0.f, mA3 = (eA3 < d1) ? 1.f : 0.f;
                float mB0 = (eB0 < d1) ? 1.f : 0.f, mB1 = (eB1 < d1) ? 1.f : 0.f;
                float mB2 = (eB2 < d1) ? 1.f : 0.f, mB3 = (eB3 < d1) ? 1.f : 0.f;
                int iA0, iA1, iA2, iA3, iB0, iB1, iB2, iB3;
                if (lds_ok) {
                    iA0 = sIdx[min(eA0, d1 - 1) - d0blk];
                    iA1 = sIdx[min(eA1, d1 - 1) - d0blk];
                    iA2 = sIdx[min(eA2, d1 - 1) - d0blk];
                    iA3 = sIdx[min(eA3, d1 - 1) - d0blk];
                    iB0 = sIdx[min(eB0, d1 - 1) - d0blk];
                    iB1 = sIdx[min(eB1, d1 - 1) - d0blk];
                    iB2 = sIdx[min(eB2, d1 - 1) - d0blk];
                    iB3 = sIdx[min(eB3, d1 - 1) - d0blk];
                } else {
                    iA0 = snbr[min(eA0, d1 - 1)];
                    iA1 = snbr[min(eA1, d1 - 1)];
                    iA2 = snbr[min(eA2, d1 - 1)];
                    iA3 = snbr[min(eA3, d1 - 1)];
                    iB0 = snbr[min(eB0, d1 - 1)];
                    iB1 = snbr[min(eB1, d1 - 1)];
                    iB2 = snbr[min(eB2, d1 - 1)];
                    iB3 = snbr[min(eB3, d1 - 1)];
                }
                half8 rA0 = *(const half8*)&reps_in[(size_t)iA0 * 32 + ch * 8];
                half8 rA1 = *(const half8*)&reps_in[(size_t)iA1 * 32 + ch * 8];
                half8 rA2 = *(const half8*)&reps_in[(size_t)iA2 * 32 + ch * 8];
                half8 rA3 = *(const half8*)&reps_in[(size_t)iA3 * 32 + ch * 8];
                half8 rB0 = *(const half8*)&reps_in[(size_t)iB0 * 32 + ch * 8];
                half8 rB1 = *(const half8*)&reps_in[(size_t)iB1 * 32 + ch * 8];
                half8 rB2 = *(const half8*)&reps_in[(size_t)iB2 * 32 + ch * 8];
                half8 rB3 = *(const half8*)&reps_in[(size_t)iB3 * 32 + ch * 8];
#pragma unroll
                for (int f = 0; f < 4; ++f) {
                    half2_t a0 = (half2_t){rA0[2 * f], rA0[2 * f + 1]};
                    half2_t a1 = (half2_t){rA1[2 * f], rA1[2 * f + 1]};
                    half2_t a2 = (half2_t){rA2[2 * f], rA2[2 * f + 1]};
                    half2_t a3 = (half2_t){rA3[2 * f], rA3[2 * f + 1]};
                    half2_t b0 = (half2_t){rB0[2 * f], rB0[2 * f + 1]};
                    half2_t b1 = (half2_t){rB1[2 * f], rB1[2 * f + 1]};
                    half2_t b2 = (half2_t){rB2[2 * f], rB2[2 * f + 1]};
                    half2_t b3 = (half2_t){rB3[2 * f], rB3[2 * f + 1]};
                    half2_t mxa = __builtin_elementwise_max(
                        __builtin_elementwise_max(a0, a1),
                        __builtin_elementwise_max(a2, a3));
                    half2_t mxb = __builtin_elementwise_max(
                        __builtin_elementwise_max(b0, b1),
                        __builtin_elementwise_max(b2, b3));
                    mx2[f] = __builtin_elementwise_max(mx2[f],
                        __builtin_elementwise_max(mxa, mxb));
                    half2_t mna = __builtin_elementwise_min(
                        __builtin_elementwise_min(a0, a1),
                        __builtin_elementwise_min(a2, a3));
                    half2_t mnb = __builtin_elementwise_min(
                        __builtin_elementwise_min(b0, b1),
                        __builtin_elementwise_min(b2, b3));
                    mn2[f] = __builtin_elementwise_min(mn2[f],
                        __builtin_elementwise_min(mna, mnb));
                }
#pragma unroll
                for (int f = 0; f < 8; ++f) {
                    s[f] = fmaf((float)rA0[f], mA0, s[f]);
                    s[f] = fmaf((float)rA1[f], mA1, s[f]);
                    s[f] = fmaf((float)rA2[f], mA2, s[f]);
                    s[f] = fmaf((float)rA3[f], mA3, s[f]);
                    s[f] = fmaf((float)rB0[f], mB0, s[f]);
                    s[f] = fmaf((float)rB1[f], mB1, s[f]);
                    s[f] = fmaf((float)rB2[f], mB2, s[f]);
                    s[f] = fmaf((float)rB3[f], mB3, s[f]);
                }
            }
            // reduce across the 4 nb slots (xor strides 4, 8 inside subgroup)
#pragma unroll
            for (int f = 0; f < 8; ++f) {
                s[f] += __shfl_xor(s[f], 4);
                s[f] += __shfl_xor(s[f], 8);
            }
#pragma unroll
            for (int f = 0; f < 4; ++f) {
                mx2[f] = __builtin_elementwise_max(mx2[f], h2shfl_xor(mx2[f], 4));
                mx2[f] = __builtin_elementwise_max(mx2[f], h2shfl_xor(mx2[f], 8));
                mn2[f] = __builtin_elementwise_min(mn2[f], h2shfl_xor(mn2[f], 4));
                mn2[f] = __builtin_elementwise_min(mn2[f], h2shfl_xor(mn2[f], 8));
            }
            float cnt = fmaxf((float)(d1 - d0), 1.f);
            half8 o;
            if (nb == 0) {
                if (node < n) {
                    o = *(const half8*)&reps_in[(size_t)node * 32 + ch * 8];
                } else {
#pragma unroll
                    for (int f = 0; f < 8; ++f) o[f] = (half_t)0.f;
                }
            } else if (nb == 1) {
                float rc = __builtin_amdgcn_rcpf(cnt);
#pragma unroll
                for (int f = 0; f < 8; ++f) o[f] = cvt_clamp(s[f] * rc);
            } else if (nb == 2) {
#pragma unroll
                for (int f = 0; f < 4; ++f) {
                    o[2 * f]     = cvt_clamp((float)mx2[f][0]);
                    o[2 * f + 1] = cvt_clamp((float)mx2[f][1]);
                }
            } else {
#pragma unroll
                for (int f = 0; f < 4; ++f) {
                    o[2 * f]     = cvt_clamp((float)mn2[f][0]);
                    o[2 * f + 1] = cvt_clamp((float)mn2[f][1]);
                }
            }
            *(half8*)&sH[nl * 136 + l * 8] = o;
        }
    }
    __syncthreads();   // gather done; sIdx dead -> sh1c reusable

    // ---- split-K: 2 chunks of {GEMM1 128 cols -> GEMM2 partial} ----
    f32x4 acc2[4] = {{0.f, 0.f, 0.f, 0.f}, {0.f, 0.f, 0.f, 0.f},
                     {0.f, 0.f, 0.f, 0.f}, {0.f, 0.f, 0.f, 0.f}};
#pragma unroll
    for (int c = 0; c < 2; ++c) {
        // GEMM1 chunk c: wave w owns h1 cols [c*128 + w*16, +16)
        {
            half8 a[4];
#pragma unroll
            for (int ks = 0; ks < 4; ++ks)
                a[ks] = *(const half8*)&Wt1[(c * 128 + w * 16 + l15) * 128 + ks * 32 + lk * 8];
            f32x4 bv = *(const f32x4*)&bu1[c * 128 + w * 16 + lk * 4];
#pragma unroll
            for (int nt = 0; nt < 4; ++nt) {
                const half_t* hrow = &sH[(nt * 16 + l15) * 136 + lk * 8];
                half8 b0 = *(const half8*)&hrow[0];
                half8 b1 = *(const half8*)&hrow[32];
                half8 b2 = *(const half8*)&hrow[64];
                half8 b3 = *(const half8*)&hrow[96];
                f32x4 acc = {0.f, 0.f, 0.f, 0.f};
                acc = MFMA16(a[0], b0, acc);
                acc = MFMA16(a[1], b1, acc);
                acc = MFMA16(a[2], b2, acc);
                acc = MFMA16(a[3], b3, acc);
                half4_t o;
#pragma unroll
                for (int r = 0; r < 4; ++r)
                    o[r] = (half_t)fast_tanh(acc[r] + bv[r]);
                *(half4_t*)&sh1c[(nt * 16 + l15) * 136 + w * 16 + lk * 4] = o;
            }
        }
        __syncthreads();   // h1 chunk ready
        // GEMM2 partial: k in [c*128, c*128+128)
        {
            half8 a[4];
#pragma unroll
            for (int ks = 0; ks < 4; ++ks)
                a[ks] = *(const half8*)&Wt2[(w * 16 + l15) * 256 + c * 128 + ks * 32 + lk * 8];
#pragma unroll
            for (int nt = 0; nt < 4; ++nt) {
#pragma unroll
                for (int ks = 0; ks < 4; ++ks) {
                    half8 b = *(const half8*)&sh1c[(nt * 16 + l15) * 136 + ks * 32 + lk * 8];
                    acc2[nt] = MFMA16(a[ks], b, acc2[nt]);
                }
            }
        }
        __syncthreads();   // chunk reads done before overwrite / sH overlay
    }

    // ---- h2 = tanh(acc2 + b2) -> overlay into sH (dead after GEMM1) ----
    {
        f32x4 bv = *(const f32x4*)&bu2[w * 16 + lk * 4];
#pragma unroll
        for (int nt = 0; nt < 4; ++nt) {
            half4_t o;
#pragma unroll
            for (int r = 0; r < 4; ++r)
                o[r] = (half_t)fast_tanh(acc2[nt][r] + bv[r]);
            *(half4_t*)&sH[(nt * 16 + l15) * 136 + w * 16 + lk * 4] = o;
        }
    }
    __syncthreads();

    // ---- GEMM3 + l2norm: waves 0..3, wave w owns nodes [w*16,(w+1)*16) ----
    if (w < 4) {
        half8 a0[4], a1[4], b[4];
#pragma unroll
        for (int ks = 0; ks < 4; ++ks) {
            a0[ks] = *(const half8*)&Wt3[l15 * 128 + ks * 32 + lk * 8];
            a1[ks] = *(const half8*)&Wt3[(16 + l15) * 128 + ks * 32 + lk * 8];
            b[ks]  = *(const half8*)&sH[(w * 16 + l15) * 136 + ks * 32 + lk * 8];
        }
        f32x4 acc0 = {0.f, 0.f, 0.f, 0.f}, acc1 = {0.f, 0.f, 0.f, 0.f};
#pragma unroll
        for (int ks = 0; ks < 4; ++ks) {
            acc0 = MFMA16(a0[ks], b[ks], acc0);
            acc1 = MFMA16(a1[ks], b[ks], acc1);
        }
        f32x4 bv0 = *(const f32x4*)&bu3[lk * 4];
        f32x4 bv1 = *(const f32x4*)&bu3[16 + lk * 4];
        float v0[4], v1[4];
        float ss = 0.f;
#pragma unroll
        for (int r = 0; r < 4; ++r) {
            v0[r] = fast_tanh(acc0[r] + bv0[r]);
            v1[r] = fast_tanh(acc1[r] + bv1[r]);
            ss += v0[r] * v0[r] + v1[r] * v1[r];
        }
        ss += __shfl_xor(ss, 16);
        ss += __shfl_xor(ss, 32);
        float sc = rsqrtf(fmaxf(ss, 1e-12f));
        int node = node0 + w * 16 + l15;
        if (node < n) {
            half4_t o0, o1;
#pragma unroll
            for (int r = 0; r < 4; ++r) {
                o0[r] = (half_t)(v0[r] * sc);
                o1[r] = (half_t)(v1[r] * sc);
            }
            *(half4_t*)&reps_out[(size_t)node * 32 + lk * 4] = o0;
            *(half4_t*)&reps_out[(size_t)node * 32 + 16 + lk * 4] = o1;
        }
    }
}

// ---------------- readout: gather generators (nan->0), 32->64->32->1 ----------------
__global__ __launch_bounds__(256) void k_readout(
    const half_t* __restrict__ reps, const int* __restrict__ gen,
    const float* __restrict__ Wr1, const float* __restrict__ br1,
    const float* __restrict__ Wr2, const float* __restrict__ br2,
    const float* __restrict__ Wr3, const float* __restrict__ br3,
    float* __restrict__ out, int ngen) {
    __shared__ float sW1[32 * 64];
    __shared__ float sW2[64 * 32];
    __shared__ float sb1[64];
    __shared__ float sb2[32];
    __shared__ float sW3r[32];
    __shared__ float sb3;
    int tid = threadIdx.x;
    for (int i = tid; i < 2048; i += 256) sW1[i] = Wr1[i];
    for (int i = tid; i < 2048; i += 256) sW2[i] = Wr2[i];
    if (tid < 64) sb1[tid] = br1[tid];
    if (tid < 32) sb2[tid] = br2[tid];
    if (tid < 32) sW3r[tid] = Wr3[tid];
    if (tid == 0) sb3 = br3[0];
    __syncthreads();
    int ig = blockIdx.x * 256 + tid;
    if (ig >= ngen) return;
    int node = gen[ig];
    float g[32];
#pragma unroll
    for (int q = 0; q < 4; ++q) {
        half8 v = *(const half8*)&reps[(size_t)node * 32 + q * 8];
#pragma unroll
        for (int r = 0; r < 8; ++r) {
            float f = (float)v[r];
            g[q * 8 + r] = (f != f) ? 0.f : f;
        }
    }
    float a[64];
#pragma unroll
    for (int o = 0; o < 64; ++o) {
        float acc = sb1[o];
#pragma unroll
        for (int k = 0; k < 32; ++k) acc = fmaf(g[k], sW1[k * 64 + o], acc);
        a[o] = fast_tanh(acc);
    }
    float b[32];
#pragma unroll
    for (int o = 0; o < 32; ++o) {
        float acc = sb2[o];
#pragma unroll
        for (int k = 0; k < 64; ++k) acc = fmaf(a[k], sW2[k * 32 + o], acc);
        b[o] = fast_tanh(acc);
    }
    float acc = sb3;
#pragma unroll
    for (int k = 0; k < 32; ++k) acc = fmaf(b[k], sW3r[k], acc);
    out[ig] = acc;
}

extern "C" void kernel_launch(void* const* d_in, const int* in_sizes, int n_in,
                              void* d_out, int out_size, void* d_ws, size_t ws_size,
                              hipStream_t stream) {
    const float* x   = (const float*)d_in[0];
    const float* ew  = (const float*)d_in[1];
    const float* Wu1 = (const float*)d_in[2];
    const float* bu1 = (const float*)d_in[3];
    const float* Wu2 = (const float*)d_in[4];
    const float* bu2 = (const float*)d_in[5];
    const float* Wu3 = (const float*)d_in[6];
    const float* bu3 = (const float*)d_in[7];
    const float* Wr1 = (const float*)d_in[8];
    const float* br1 = (const float*)d_in[9];
    const float* Wr2 = (const float*)d_in[10];
    const float* br2 = (const float*)d_in[11];
    const float* Wr3 = (const float*)d_in[12];
    const float* br3 = (const float*)d_in[13];
    const int* edges = (const int*)d_in[14];
    const int* gen   = (const int*)d_in[15];

    const int n    = in_sizes[0] / 8;
    const int E    = in_sizes[1] / 4;
    const int ngen = in_sizes[15];
    const int* dst = edges;      // node_idx (segment ids)
    const int* src = edges + E;  // nbr_idx (gather source)
    float* out = (float*)d_out;

    const int nblk  = (n + 63) / 64;
    const int npad  = nblk * 64;
    const int nbins = (n + NPB - 1) / NPB;

    // workspace layout (256B aligned slabs)
    char* ws = (char*)d_ws;
    size_t off = 0;
    auto alloc = [&](size_t bytes) -> char* {
        char* p = ws + off;
        off = (off + bytes + 255) & ~(size_t)255;
        return p;
    };
    int* row_start = (int*)alloc((size_t)(n + 1) * 4);
    int* binCnt    = (int*)alloc(256 * 4);
    int* binStart  = (int*)alloc(256 * 4);
    int* snbr      = (int*)alloc((size_t)E * 4);
    half_t* repsA  = (half_t*)alloc((size_t)npad * 32 * 2);
    half_t* repsB  = (half_t*)alloc((size_t)npad * 32 * 2);
    half_t* Wt1    = (half_t*)alloc(32768 * 2);
    half_t* Wt2    = (half_t*)alloc(32768 * 2);
    half_t* Wt3    = (half_t*)alloc(4096 * 2);
    int4* staged   = (int4*)alloc((size_t)nbins * BIN_CAP * 16);   // CSR build only

    // ---- CSR build (binned) + stats + reps ----
    hipMemsetAsync(binCnt, 0, 256 * 4, stream);
    int nblkA = (E + 8191) / 8192;
    k_binA<<<nblkA, 256, 0, stream>>>(dst, src, (const float4*)ew, binCnt, staged, E, nbins);
    k_scanN<<<1, 256, 0, stream>>>(binCnt, binStart, row_start, nbins, n, E);
    k_binB<<<nbins, 1024, 0, stream>>>(binCnt, binStart, staged, x,
                                       row_start, snbr, repsA, n);
    k_wprep<<<272, 256, 0, stream>>>(Wu1, Wu2, Wu3, Wt1, Wt2, Wt3);

    half_t* cur = repsA;
    half_t* nxt = repsB;
    for (int it = 0; it < 3; ++it) {
        k_mlp<<<nblk, 512, 0, stream>>>(cur, row_start, snbr, Wt1, Wt2, Wt3,
                                        bu1, bu2, bu3, nxt, n);
        half_t* t = cur; cur = nxt; nxt = t;
    }

    k_readout<<<(ngen + 255) / 256, 256, 0, stream>>>(cur, gen, Wr1, br1, Wr2, br2,
                                                      Wr3, br3, out, ngen);
}

// Round 12
// 330.960 us; speedup vs baseline: 1.5086x; 1.5086x over previous
//
#include <hip/hip_runtime.h>
#include <cfloat>
#include <cmath>

// ---------------------------------------------------------------------------
// GNN message passing — fp16 MFMA, round 12.
//  R12 = surgical revert of r11's change 2. The 32-edge gather unroll blew the
//  84-VGPR cap -> scratch spills (WRITE 6.25->154MB sentinel fired). Gather is
//  back to r10's spill-free 16-edge loop. r11's change 1 is KEPT (binA packs
//  fp16 ew into staged int4; binB 1024 threads, zero random reads) so this
//  round's profile isolates its true effect.
// MFMA mapping (verified r3-r10): D=A*B, A=W^T[nout][k], B=H[node][k]; D:
// col=lane&15=node, row=(lane>>4)*4+reg=nout.
// ---------------------------------------------------------------------------

typedef _Float16 half_t;
typedef _Float16 half8 __attribute__((ext_vector_type(8)));
typedef _Float16 half4_t __attribute__((ext_vector_type(4)));
typedef _Float16 half2_t __attribute__((ext_vector_type(2)));
typedef float f32x4 __attribute__((ext_vector_type(4)));

#define NPB 512       // nodes per bin (power of 2: bin = dst>>9)
#define BIN_CAP 9216  // slots per bin; mean 8163, sd ~90 -> +11.7 sigma
#define IDXCAP 4352   // LDS idx slots per k_mlp block (mean 1024)

__device__ __forceinline__ float fast_tanh(float x) {
    float e = __builtin_amdgcn_exp2f(x * 2.8853900817779268f);
    return 1.0f - 2.0f * __builtin_amdgcn_rcpf(1.0f + e);
}

__device__ __forceinline__ half_t cvt_clamp(float v) {
    return (half_t)fminf(fmaxf(v, -60000.f), 60000.f);
}

__device__ __forceinline__ half2_t h2shfl_xor(half2_t v, int mask) {
    int i = __builtin_bit_cast(int, v);
    i = __shfl_xor(i, mask);
    return __builtin_bit_cast(half2_t, i);
}

// ---------------- phase A: bin edges + pack fp16 ew (coalesced staging) ----------------
__global__ __launch_bounds__(256) void k_binA(
    const int* __restrict__ dst, const int* __restrict__ src,
    const float4* __restrict__ ew4,
    int* __restrict__ binCnt, int4* __restrict__ staged, int E, int nbins) {
    __shared__ int cnt[256], base[256], cur[256];
    int t = threadIdx.x;
    cnt[t] = 0;
    cur[t] = 0;
    __syncthreads();
    int e0 = blockIdx.x * 8192;
#pragma unroll 4
    for (int i = 0; i < 32; ++i) {
        int e = e0 + i * 256 + t;
        if (e < E) atomicAdd(&cnt[dst[e] >> 9], 1);
    }
    __syncthreads();
    if (t < nbins && cnt[t] > 0) base[t] = atomicAdd(&binCnt[t], cnt[t]);
    __syncthreads();
#pragma unroll 4
    for (int i = 0; i < 32; ++i) {
        int e = e0 + i * 256 + t;
        if (e < E) {
            int d = dst[e];
            int b = d >> 9;
            int j = base[b] + atomicAdd(&cur[b], 1);
            if (j < BIN_CAP) {
                float4 w = ew4[e];   // coalesced here (e sequential)
                half2_t lo = {(half_t)w.x, (half_t)w.y};
                half2_t hi = {(half_t)w.z, (half_t)w.w};
                staged[(size_t)b * BIN_CAP + j] =
                    make_int4(src[e], d & (NPB - 1),
                              __builtin_bit_cast(int, lo),
                              __builtin_bit_cast(int, hi));
            }
        }
    }
}

// ---------------- bin-count exclusive scan (nbins <= 256) ----------------
__global__ void k_scanN(const int* __restrict__ binCnt, int* __restrict__ binStart,
                        int* __restrict__ row_start, int nbins, int n, int E) {
    __shared__ int sh[256];
    int t = threadIdx.x;
    int v = (t < nbins) ? binCnt[t] : 0;
    sh[t] = v;
    __syncthreads();
    for (int s = 1; s < 256; s <<= 1) {
        int u = (t >= s) ? sh[t - s] : 0;
        __syncthreads();
        sh[t] += u;
        __syncthreads();
    }
    if (t < nbins) binStart[t] = sh[t] - v;
    if (t == 0) row_start[n] = E;
}

// ---------------- phase B: per-bin CSR + stats (all from staged) + reps ----------------
__global__ __launch_bounds__(1024) void k_binB(
    const int* __restrict__ binCnt, const int* __restrict__ binStart,
    const int4* __restrict__ staged, const float* __restrict__ x,
    int* __restrict__ row_start, int* __restrict__ snbr,
    half_t* __restrict__ reps, int n) {
    __shared__ int deg[NPB], cur[NPB], rsl[NPB];
    __shared__ float ssum[NPB * 4];
    __shared__ int smax[NPB * 4], smin[NPB * 4];   // fp16 bits (ew >= 0)
    int t = threadIdx.x;
    int bin = blockIdx.x;
    int cntE = min(binCnt[bin], BIN_CAP);
    int pbase = binStart[bin];
    const int4* st = staged + (size_t)bin * BIN_CAP;

    if (t < NPB) { deg[t] = 0; cur[t] = 0; }
    for (int i = t; i < NPB * 4; i += 1024) {
        ssum[i] = 0.f;
        smax[i] = 0;         // fp16 +0 (ew >= 0 lower bound)
        smin[i] = 0x7BFF;    // fp16 65504 bits
    }
    __syncthreads();

    // pass 1: degree count + stats (coalesced staged reads, no random loads)
    for (int i = t; i < cntE; i += 1024) {
        int4 v = st[i];
        int dl = v.y;
        atomicAdd(&deg[dl], 1);
        int b0 = v.z & 0xFFFF, b1 = (v.z >> 16) & 0xFFFF;
        int b2 = v.w & 0xFFFF, b3 = (v.w >> 16) & 0xFFFF;
        half2_t lo = __builtin_bit_cast(half2_t, v.z);
        half2_t hi = __builtin_bit_cast(half2_t, v.w);
        atomicAdd(&ssum[dl * 4 + 0], (float)lo[0]);
        atomicAdd(&ssum[dl * 4 + 1], (float)lo[1]);
        atomicAdd(&ssum[dl * 4 + 2], (float)hi[0]);
        atomicAdd(&ssum[dl * 4 + 3], (float)hi[1]);
        atomicMax(&smax[dl * 4 + 0], b0);
        atomicMax(&smax[dl * 4 + 1], b1);
        atomicMax(&smax[dl * 4 + 2], b2);
        atomicMax(&smax[dl * 4 + 3], b3);
        atomicMin(&smin[dl * 4 + 0], b0);
        atomicMin(&smin[dl * 4 + 1], b1);
        atomicMin(&smin[dl * 4 + 2], b2);
        atomicMin(&smin[dl * 4 + 3], b3);
    }
    __syncthreads();

    int own = (t < NPB) ? deg[t] : 0;
    for (int s = 1; s < NPB; s <<= 1) {   // inclusive Hillis-Steele (t<512 active)
        int u = (t < NPB && t >= s) ? deg[t - s] : 0;
        __syncthreads();
        if (t < NPB) deg[t] += u;
        __syncthreads();
    }
    int node = bin * NPB + t;
    if (t < NPB) {
        int excl = deg[t] - own;
        rsl[t] = pbase + excl;
        if (node < n) row_start[node] = pbase + excl;
    }
    __syncthreads();

    // scatter pass: snbr only
    for (int i = t; i < cntE; i += 1024) {
        int4 v = st[i];
        int p = rsl[v.y] + atomicAdd(&cur[v.y], 1);
        snbr[p] = v.x;
    }

    // reps row: [x(8), mean(4), max(4), min(4), sum(4), 0(8)] in fp16
    if (t < NPB && node < n) {
        float cnt = fmaxf((float)own, 1.0f);
        float rc = __builtin_amdgcn_rcpf(cnt);
        float sm0 = ssum[t * 4 + 0], sm1 = ssum[t * 4 + 1];
        float sm2 = ssum[t * 4 + 2], sm3 = ssum[t * 4 + 3];
        float mx0, mx1, mx2, mx3, mn0, mn1, mn2, mn3;
        if (own == 0) {
            mx0 = mx1 = mx2 = mx3 = -FLT_MAX;
            mn0 = mn1 = mn2 = mn3 = FLT_MAX;
        } else {
            mx0 = (float)__builtin_bit_cast(half_t, (unsigned short)smax[t * 4 + 0]);
            mx1 = (float)__builtin_bit_cast(half_t, (unsigned short)smax[t * 4 + 1]);
            mx2 = (float)__builtin_bit_cast(half_t, (unsigned short)smax[t * 4 + 2]);
            mx3 = (float)__builtin_bit_cast(half_t, (unsigned short)smax[t * 4 + 3]);
            mn0 = (float)__builtin_bit_cast(half_t, (unsigned short)smin[t * 4 + 0]);
            mn1 = (float)__builtin_bit_cast(half_t, (unsigned short)smin[t * 4 + 1]);
            mn2 = (float)__builtin_bit_cast(half_t, (unsigned short)smin[t * 4 + 2]);
            mn3 = (float)__builtin_bit_cast(half_t, (unsigned short)smin[t * 4 + 3]);
        }
        const float4* x4 = reinterpret_cast<const float4*>(x);
        float4 x0 = x4[node * 2 + 0], x1 = x4[node * 2 + 1];
        half_t* o = &reps[(size_t)node * 32];
        half8 c0 = {cvt_clamp(x0.x), cvt_clamp(x0.y), cvt_clamp(x0.z), cvt_clamp(x0.w),
                    cvt_clamp(x1.x), cvt_clamp(x1.y), cvt_clamp(x1.z), cvt_clamp(x1.w)};
        half8 c1 = {cvt_clamp(sm0 * rc), cvt_clamp(sm1 * rc), cvt_clamp(sm2 * rc), cvt_clamp(sm3 * rc),
                    cvt_clamp(mx0), cvt_clamp(mx1), cvt_clamp(mx2), cvt_clamp(mx3)};
        half8 c2 = {cvt_clamp(mn0), cvt_clamp(mn1), cvt_clamp(mn2), cvt_clamp(mn3),
                    cvt_clamp(sm0), cvt_clamp(sm1), cvt_clamp(sm2), cvt_clamp(sm3)};
        half8 c3 = {(half_t)0.f, (half_t)0.f, (half_t)0.f, (half_t)0.f,
                    (half_t)0.f, (half_t)0.f, (half_t)0.f, (half_t)0.f};
        *(half8*)&o[0] = c0;
        *(half8*)&o[8] = c1;
        *(half8*)&o[16] = c2;
        *(half8*)&o[24] = c3;
    }
}

// ---------------- weight prep: fp32 [k][n] -> fp16 [n][k] ----------------
__global__ void k_wprep(const float* __restrict__ Wu1, const float* __restrict__ Wu2,
                        const float* __restrict__ Wu3, half_t* __restrict__ Wt1,
                        half_t* __restrict__ Wt2, half_t* __restrict__ Wt3) {
    int i = blockIdx.x * 256 + threadIdx.x;
    if (i < 32768) {
        int nrow = i >> 7, k = i & 127;
        Wt1[i] = (half_t)Wu1[k * 256 + nrow];
    } else if (i < 65536) {
        int j = i - 32768;
        int nrow = j >> 8, k = j & 255;
        Wt2[j] = (half_t)Wu2[k * 128 + nrow];
    } else if (i < 69632) {
        int j = i - 65536;
        int nrow = j >> 7, k = j & 127;
        Wt3[j] = (half_t)Wu3[k * 32 + nrow];
    }
}

// ---------------- fused iter: LDS-idx gather + split-K MFMA MLP + l2norm ----------------
#define MFMA16(a, b, c) __builtin_amdgcn_mfma_f32_16x16x32_f16((a), (b), (c), 0, 0, 0)

__global__ __launch_bounds__(512, 6) void k_mlp(
    const half_t* __restrict__ reps_in,
    const int* __restrict__ row_start, const int* __restrict__ snbr,
    const half_t* __restrict__ Wt1, const half_t* __restrict__ Wt2,
    const half_t* __restrict__ Wt3,
    const float* __restrict__ bu1, const float* __restrict__ bu2,
    const float* __restrict__ bu3,
    half_t* __restrict__ reps_out, int n) {
    __shared__ half_t sH[64 * 136];     // H[64][128]; later h2[64][128]
    __shared__ half_t sh1c[64 * 136];   // idx stage, then h1 chunk [64][128]
    int* sIdx = (int*)sh1c;             // 4352 int slots

    const int tid = threadIdx.x;
    const int w   = tid >> 6;
    const int l15 = tid & 15;
    const int lk  = (tid & 63) >> 4;
    const int node0 = blockIdx.x * 64;

    // ---- idx stage: block's CSR range is contiguous -> coalesced LDS burst ----
    const int nodeEnd = min(node0 + 64, n);
    const int d0blk = row_start[node0];
    const int ecnt = row_start[nodeEnd] - d0blk;
    const bool lds_ok = (ecnt <= IDXCAP);
    if (lds_ok) {
        for (int i = tid; i < ecnt; i += 512)
            sIdx[i] = __builtin_nontemporal_load(&snbr[d0blk + i]);
    }
    __syncthreads();

    // ---- gather: 32 subgroups of 16 lanes; lane=(nb,ch); 16 edges/iter ----
    // (r10's spill-free shape: 4 rows in flight per lane.)
    {
        const int sg = tid >> 4;
        const int l  = tid & 15;
        const int nb = l >> 2;
        const int ch = l & 3;

        for (int i = 0; i < 2; ++i) {
            int nl = i * 32 + sg;
            int node = node0 + nl;
            float s[8];
            half2_t mx2[4], mn2[4];
#pragma unroll
            for (int f = 0; f < 8; ++f) s[f] = 0.f;
#pragma unroll
            for (int f = 0; f < 4; ++f) {
                mx2[f] = (half2_t){(half_t)-65504.f, (half_t)-65504.f};
                mn2[f] = (half2_t){(half_t)65504.f, (half_t)65504.f};
            }
            int d0 = 0, d1 = 0;
            if (node < n) { d0 = row_start[node]; d1 = row_start[node + 1]; }

            for (int e = d0; e < d1; e += 16) {
                int e0 = e + nb, e1 = e + 4 + nb, e2 = e + 8 + nb, e3 = e + 12 + nb;
                float m0 = (e0 < d1) ? 1.f : 0.f;
                float m1 = (e1 < d1) ? 1.f : 0.f;
                float m2 = (e2 < d1) ? 1.f : 0.f;
                float m3 = (e3 < d1) ? 1.f : 0.f;
                int ii0, ii1, ii2, ii3;
                if (lds_ok) {
                    ii0 = sIdx[min(e0, d1 - 1) - d0blk];
                    ii1 = sIdx[min(e1, d1 - 1) - d0blk];
                    ii2 = sIdx[min(e2, d1 - 1) - d0blk];
                    ii3 = sIdx[min(e3, d1 - 1) - d0blk];
                } else {
                    ii0 = snbr[min(e0, d1 - 1)];
                    ii1 = snbr[min(e1, d1 - 1)];
                    ii2 = snbr[min(e2, d1 - 1)];
                    ii3 = snbr[min(e3, d1 - 1)];
                }
                half8 r0 = *(const half8*)&reps_in[(size_t)ii0 * 32 + ch * 8];
                half8 r1 = *(const half8*)&reps_in[(size_t)ii1 * 32 + ch * 8];
                half8 r2 = *(const half8*)&reps_in[(size_t)ii2 * 32 + ch * 8];
                half8 r3 = *(const half8*)&reps_in[(size_t)ii3 * 32 + ch * 8];
#pragma unroll
                for (int f = 0; f < 4; ++f) {
                    half2_t a0 = (half2_t){r0[2 * f], r0[2 * f + 1]};
                    half2_t a1 = (half2_t){r1[2 * f], r1[2 * f + 1]};
                    half2_t a2 = (half2_t){r2[2 * f], r2[2 * f + 1]};
                    half2_t a3 = (half2_t){r3[2 * f], r3[2 * f + 1]};
                    mx2[f] = __builtin_elementwise_max(
                        __builtin_elementwise_max(mx2[f], a0),
                        __builtin_elementwise_max(a1,
                            __builtin_elementwise_max(a2, a3)));
                    mn2[f] = __builtin_elementwise_min(
                        __builtin_elementwise_min(mn2[f], a0),
                        __builtin_elementwise_min(a1,
                            __builtin_elementwise_min(a2, a3)));
                }
#pragma unroll
                for (int f = 0; f < 8; ++f) {
                    s[f] = fmaf((float)r0[f], m0, s[f]);
                    s[f] = fmaf((float)r1[f], m1, s[f]);
                    s[f] = fmaf((float)r2[f], m2, s[f]);
                    s[f] = fmaf((float)r3[f], m3, s[f]);
                }
            }
            // reduce across the 4 nb slots (xor strides 4, 8 inside subgroup)
#pragma unroll
            for (int f = 0; f < 8; ++f) {
                s[f] += __shfl_xor(s[f], 4);
                s[f] += __shfl_xor(s[f], 8);
            }
#pragma unroll
            for (int f = 0; f < 4; ++f) {
                mx2[f] = __builtin_elementwise_max(mx2[f], h2shfl_xor(mx2[f], 4));
                mx2[f] = __builtin_elementwise_max(mx2[f], h2shfl_xor(mx2[f], 8));
                mn2[f] = __builtin_elementwise_min(mn2[f], h2shfl_xor(mn2[f], 4));
                mn2[f] = __builtin_elementwise_min(mn2[f], h2shfl_xor(mn2[f], 8));
            }
            float cnt = fmaxf((float)(d1 - d0), 1.f);
            half8 o;
            if (nb == 0) {
                if (node < n) {
                    o = *(const half8*)&reps_in[(size_t)node * 32 + ch * 8];
                } else {
#pragma unroll
                    for (int f = 0; f < 8; ++f) o[f] = (half_t)0.f;
                }
            } else if (nb == 1) {
                float rc = __builtin_amdgcn_rcpf(cnt);
#pragma unroll
                for (int f = 0; f < 8; ++f) o[f] = cvt_clamp(s[f] * rc);
            } else if (nb == 2) {
#pragma unroll
                for (int f = 0; f < 4; ++f) {
                    o[2 * f]     = cvt_clamp((float)mx2[f][0]);
                    o[2 * f + 1] = cvt_clamp((float)mx2[f][1]);
                }
            } else {
#pragma unroll
                for (int f = 0; f < 4; ++f) {
                    o[2 * f]     = cvt_clamp((float)mn2[f][0]);
                    o[2 * f + 1] = cvt_clamp((float)mn2[f][1]);
                }
            }
            *(half8*)&sH[nl * 136 + l * 8] = o;
        }
    }
    __syncthreads();   // gather done; sIdx dead -> sh1c reusable

    // ---- split-K: 2 chunks of {GEMM1 128 cols -> GEMM2 partial} ----
    f32x4 acc2[4] = {{0.f, 0.f, 0.f, 0.f}, {0.f, 0.f, 0.f, 0.f},
                     {0.f, 0.f, 0.f, 0.f}, {0.f, 0.f, 0.f, 0.f}};
#pragma unroll
    for (int c = 0; c < 2; ++c) {
        // GEMM1 chunk c: wave w owns h1 cols [c*128 + w*16, +16)
        {
            half8 a[4];
#pragma unroll
            for (int ks = 0; ks < 4; ++ks)
                a[ks] = *(const half8*)&Wt1[(c * 128 + w * 16 + l15) * 128 + ks * 32 + lk * 8];
            f32x4 bv = *(const f32x4*)&bu1[c * 128 + w * 16 + lk * 4];
#pragma unroll
            for (int nt = 0; nt < 4; ++nt) {
                const half_t* hrow = &sH[(nt * 16 + l15) * 136 + lk * 8];
                half8 b0 = *(const half8*)&hrow[0];
                half8 b1 = *(const half8*)&hrow[32];
                half8 b2 = *(const half8*)&hrow[64];
                half8 b3 = *(const half8*)&hrow[96];
                f32x4 acc = {0.f, 0.f, 0.f, 0.f};
                acc = MFMA16(a[0], b0, acc);
                acc = MFMA16(a[1], b1, acc);
                acc = MFMA16(a[2], b2, acc);
                acc = MFMA16(a[3], b3, acc);
                half4_t o;
#pragma unroll
                for (int r = 0; r < 4; ++r)
                    o[r] = (half_t)fast_tanh(acc[r] + bv[r]);
                *(half4_t*)&sh1c[(nt * 16 + l15) * 136 + w * 16 + lk * 4] = o;
            }
        }
        __syncthreads();   // h1 chunk ready
        // GEMM2 partial: k in [c*128, c*128+128)
        {
            half8 a[4];
#pragma unroll
            for (int ks = 0; ks < 4; ++ks)
                a[ks] = *(const half8*)&Wt2[(w * 16 + l15) * 256 + c * 128 + ks * 32 + lk * 8];
#pragma unroll
            for (int nt = 0; nt < 4; ++nt) {
#pragma unroll
                for (int ks = 0; ks < 4; ++ks) {
                    half8 b = *(const half8*)&sh1c[(nt * 16 + l15) * 136 + ks * 32 + lk * 8];
                    acc2[nt] = MFMA16(a[ks], b, acc2[nt]);
                }
            }
        }
        __syncthreads();   // chunk reads done before overwrite / sH overlay
    }

    // ---- h2 = tanh(acc2 + b2) -> overlay into sH (dead after GEMM1) ----
    {
        f32x4 bv = *(const f32x4*)&bu2[w * 16 + lk * 4];
#pragma unroll
        for (int nt = 0; nt < 4; ++nt) {
            half4_t o;
#pragma unroll
            for (int r = 0; r < 4; ++r)
                o[r] = (half_t)fast_tanh(acc2[nt][r] + bv[r]);
            *(half4_t*)&sH[(nt * 16 + l15) * 136 + w * 16 + lk * 4] = o;
        }
    }
    __syncthreads();

    // ---- GEMM3 + l2norm: waves 0..3, wave w owns nodes [w*16,(w+1)*16) ----
    if (w < 4) {
        half8 a0[4], a1[4], b[4];
#pragma unroll
        for (int ks = 0; ks < 4; ++ks) {
            a0[ks] = *(const half8*)&Wt3[l15 * 128 + ks * 32 + lk * 8];
            a1[ks] = *(const half8*)&Wt3[(16 + l15) * 128 + ks * 32 + lk * 8];
            b[ks]  = *(const half8*)&sH[(w * 16 + l15) * 136 + ks * 32 + lk * 8];
        }
        f32x4 acc0 = {0.f, 0.f, 0.f, 0.f}, acc1 = {0.f, 0.f, 0.f, 0.f};
#pragma unroll
        for (int ks = 0; ks < 4; ++ks) {
            acc0 = MFMA16(a0[ks], b[ks], acc0);
            acc1 = MFMA16(a1[ks], b[ks], acc1);
        }
        f32x4 bv0 = *(const f32x4*)&bu3[lk * 4];
        f32x4 bv1 = *(const f32x4*)&bu3[16 + lk * 4];
        float v0[4], v1[4];
        float ss = 0.f;
#pragma unroll
        for (int r = 0; r < 4; ++r) {
            v0[r] = fast_tanh(acc0[r] + bv0[r]);
            v1[r] = fast_tanh(acc1[r] + bv1[r]);
            ss += v0[r] * v0[r] + v1[r] * v1[r];
        }
        ss += __shfl_xor(ss, 16);
        ss += __shfl_xor(ss, 32);
        float sc = rsqrtf(fmaxf(ss, 1e-12f));
        int node = node0 + w * 16 + l15;
        if (node < n) {
            half4_t o0, o1;
#pragma unroll
            for (int r = 0; r < 4; ++r) {
                o0[r] = (half_t)(v0[r] * sc);
                o1[r] = (half_t)(v1[r] * sc);
            }
            *(half4_t*)&reps_out[(size_t)node * 32 + lk * 4] = o0;
            *(half4_t*)&reps_out[(size_t)node * 32 + 16 + lk * 4] = o1;
        }
    }
}

// ---------------- readout: gather generators (nan->0), 32->64->32->1 ----------------
__global__ __launch_bounds__(256) void k_readout(
    const half_t* __restrict__ reps, const int* __restrict__ gen,
    const float* __restrict__ Wr1, const float* __restrict__ br1,
    const float* __restrict__ Wr2, const float* __restrict__ br2,
    const float* __restrict__ Wr3, const float* __restrict__ br3,
    float* __restrict__ out, int ngen) {
    __shared__ float sW1[32 * 64];
    __shared__ float sW2[64 * 32];
    __shared__ float sb1[64];
    __shared__ float sb2[32];
    __shared__ float sW3r[32];
    __shared__ float sb3;
    int tid = threadIdx.x;
    for (int i = tid; i < 2048; i += 256) sW1[i] = Wr1[i];
    for (int i = tid; i < 2048; i += 256) sW2[i] = Wr2[i];
    if (tid < 64) sb1[tid] = br1[tid];
    if (tid < 32) sb2[tid] = br2[tid];
    if (tid < 32) sW3r[tid] = Wr3[tid];
    if (tid == 0) sb3 = br3[0];
    __syncthreads();
    int ig = blockIdx.x * 256 + tid;
    if (ig >= ngen) return;
    int node = gen[ig];
    float g[32];
#pragma unroll
    for (int q = 0; q < 4; ++q) {
        half8 v = *(const half8*)&reps[(size_t)node * 32 + q * 8];
#pragma unroll
        for (int r = 0; r < 8; ++r) {
            float f = (float)v[r];
            g[q * 8 + r] = (f != f) ? 0.f : f;
        }
    }
    float a[64];
#pragma unroll
    for (int o = 0; o < 64; ++o) {
        float acc = sb1[o];
#pragma unroll
        for (int k = 0; k < 32; ++k) acc = fmaf(g[k], sW1[k * 64 + o], acc);
        a[o] = fast_tanh(acc);
    }
    float b[32];
#pragma unroll
    for (int o = 0; o < 32; ++o) {
        float acc = sb2[o];
#pragma unroll
        for (int k = 0; k < 64; ++k) acc = fmaf(a[k], sW2[k * 32 + o], acc);
        b[o] = fast_tanh(acc);
    }
    float acc = sb3;
#pragma unroll
    for (int k = 0; k < 32; ++k) acc = fmaf(b[k], sW3r[k], acc);
    out[ig] = acc;
}

extern "C" void kernel_launch(void* const* d_in, const int* in_sizes, int n_in,
                              void* d_out, int out_size, void* d_ws, size_t ws_size,
                              hipStream_t stream) {
    const float* x   = (const float*)d_in[0];
    const float* ew  = (const float*)d_in[1];
    const float* Wu1 = (const float*)d_in[2];
    const float* bu1 = (const float*)d_in[3];
    const float* Wu2 = (const float*)d_in[4];
    const float* bu2 = (const float*)d_in[5];
    const float* Wu3 = (const float*)d_in[6];
    const float* bu3 = (const float*)d_in[7];
    const float* Wr1 = (const float*)d_in[8];
    const float* br1 = (const float*)d_in[9];
    const float* Wr2 = (const float*)d_in[10];
    const float* br2 = (const float*)d_in[11];
    const float* Wr3 = (const float*)d_in[12];
    const float* br3 = (const float*)d_in[13];
    const int* edges = (const int*)d_in[14];
    const int* gen   = (const int*)d_in[15];

    const int n    = in_sizes[0] / 8;
    const int E    = in_sizes[1] / 4;
    const int ngen = in_sizes[15];
    const int* dst = edges;      // node_idx (segment ids)
    const int* src = edges + E;  // nbr_idx (gather source)
    float* out = (float*)d_out;

    const int nblk  = (n + 63) / 64;
    const int npad  = nblk * 64;
    const int nbins = (n + NPB - 1) / NPB;

    // workspace layout (256B aligned slabs)
    char* ws = (char*)d_ws;
    size_t off = 0;
    auto alloc = [&](size_t bytes) -> char* {
        char* p = ws + off;
        off = (off + bytes + 255) & ~(size_t)255;
        return p;
    };
    int* row_start = (int*)alloc((size_t)(n + 1) * 4);
    int* binCnt    = (int*)alloc(256 * 4);
    int* binStart  = (int*)alloc(256 * 4);
    int* snbr      = (int*)alloc((size_t)E * 4);
    half_t* repsA  = (half_t*)alloc((size_t)npad * 32 * 2);
    half_t* repsB  = (half_t*)alloc((size_t)npad * 32 * 2);
    half_t* Wt1    = (half_t*)alloc(32768 * 2);
    half_t* Wt2    = (half_t*)alloc(32768 * 2);
    half_t* Wt3    = (half_t*)alloc(4096 * 2);
    int4* staged   = (int4*)alloc((size_t)nbins * BIN_CAP * 16);   // CSR build only

    // ---- CSR build (binned) + stats + reps ----
    hipMemsetAsync(binCnt, 0, 256 * 4, stream);
    int nblkA = (E + 8191) / 8192;
    k_binA<<<nblkA, 256, 0, stream>>>(dst, src, (const float4*)ew, binCnt, staged, E, nbins);
    k_scanN<<<1, 256, 0, stream>>>(binCnt, binStart, row_start, nbins, n, E);
    k_binB<<<nbins, 1024, 0, stream>>>(binCnt, binStart, staged, x,
                                       row_start, snbr, repsA, n);
    k_wprep<<<272, 256, 0, stream>>>(Wu1, Wu2, Wu3, Wt1, Wt2, Wt3);

    half_t* cur = repsA;
    half_t* nxt = repsB;
    for (int it = 0; it < 3; ++it) {
        k_mlp<<<nblk, 512, 0, stream>>>(cur, row_start, snbr, Wt1, Wt2, Wt3,
                                        bu1, bu2, bu3, nxt, n);
        half_t* t = cur; cur = nxt; nxt = t;
    }

    k_readout<<<(ngen + 255) / 256, 256, 0, stream>>>(cur, gen, Wr1, br1, Wr2, br2,
                                                      Wr3, br3, out, ngen);
}

// Round 13
// 307.945 us; speedup vs baseline: 1.6214x; 1.0747x over previous
//
#include <hip/hip_runtime.h>
#include <cfloat>
#include <cmath>

// ---------------------------------------------------------------------------
// GNN message passing — fp16 MFMA, round 13.
//  R13 changes (two kernels, independently attributable):
//   1. k_mlp: degree-ranked subgroup mapping. Wave = 4 subgroups with
//      independent gather trip counts (ceil(deg/16), deg~Poisson(16)) -> wave
//      runs the max, wasting ~25% issue on exec-masked iterations. Rank the
//      64 nodes by degree in LDS and assign subgroups by rank: waves process
//      degree-adjacent nodes; pad/empty nodes concentrate into idle waves.
//      Bit-identical output (only processing order permuted).
//   2. k_binB: 13 -> 2 LDS atomics/edge. Pass 2 scatters packed fp16 ew into
//      sew[] next to snbr (bin window L2-hot); pass 3 computes per-node stats
//      by a sequential register walk of the node's contiguous range. No
//      stat atomics, no random reads.
// MFMA mapping (verified r3-r12): D=A*B, A=W^T[nout][k], B=H[node][k]; D:
// col=lane&15=node, row=(lane>>4)*4+reg=nout.
// ---------------------------------------------------------------------------

typedef _Float16 half_t;
typedef _Float16 half8 __attribute__((ext_vector_type(8)));
typedef _Float16 half4_t __attribute__((ext_vector_type(4)));
typedef _Float16 half2_t __attribute__((ext_vector_type(2)));
typedef float f32x4 __attribute__((ext_vector_type(4)));

#define NPB 512       // nodes per bin (power of 2: bin = dst>>9)
#define BIN_CAP 9216  // slots per bin; mean 8163, sd ~90 -> +11.7 sigma
#define IDXCAP 4352   // LDS idx slots per k_mlp block (mean 1024)

__device__ __forceinline__ float fast_tanh(float x) {
    float e = __builtin_amdgcn_exp2f(x * 2.8853900817779268f);
    return 1.0f - 2.0f * __builtin_amdgcn_rcpf(1.0f + e);
}

__device__ __forceinline__ half_t cvt_clamp(float v) {
    return (half_t)fminf(fmaxf(v, -60000.f), 60000.f);
}

__device__ __forceinline__ half2_t h2shfl_xor(half2_t v, int mask) {
    int i = __builtin_bit_cast(int, v);
    i = __shfl_xor(i, mask);
    return __builtin_bit_cast(half2_t, i);
}

// ---------------- phase A: bin edges + pack fp16 ew (coalesced staging) ----------------
__global__ __launch_bounds__(256) void k_binA(
    const int* __restrict__ dst, const int* __restrict__ src,
    const float4* __restrict__ ew4,
    int* __restrict__ binCnt, int4* __restrict__ staged, int E, int nbins) {
    __shared__ int cnt[256], base[256], cur[256];
    int t = threadIdx.x;
    cnt[t] = 0;
    cur[t] = 0;
    __syncthreads();
    int e0 = blockIdx.x * 8192;
#pragma unroll 4
    for (int i = 0; i < 32; ++i) {
        int e = e0 + i * 256 + t;
        if (e < E) atomicAdd(&cnt[dst[e] >> 9], 1);
    }
    __syncthreads();
    if (t < nbins && cnt[t] > 0) base[t] = atomicAdd(&binCnt[t], cnt[t]);
    __syncthreads();
#pragma unroll 4
    for (int i = 0; i < 32; ++i) {
        int e = e0 + i * 256 + t;
        if (e < E) {
            int d = dst[e];
            int b = d >> 9;
            int j = base[b] + atomicAdd(&cur[b], 1);
            if (j < BIN_CAP) {
                float4 w = ew4[e];   // coalesced here (e sequential)
                half2_t lo = {(half_t)w.x, (half_t)w.y};
                half2_t hi = {(half_t)w.z, (half_t)w.w};
                staged[(size_t)b * BIN_CAP + j] =
                    make_int4(src[e], d & (NPB - 1),
                              __builtin_bit_cast(int, lo),
                              __builtin_bit_cast(int, hi));
            }
        }
    }
}

// ---------------- bin-count exclusive scan (nbins <= 256) ----------------
__global__ void k_scanN(const int* __restrict__ binCnt, int* __restrict__ binStart,
                        int* __restrict__ row_start, int nbins, int n, int E) {
    __shared__ int sh[256];
    int t = threadIdx.x;
    int v = (t < nbins) ? binCnt[t] : 0;
    sh[t] = v;
    __syncthreads();
    for (int s = 1; s < 256; s <<= 1) {
        int u = (t >= s) ? sh[t - s] : 0;
        __syncthreads();
        sh[t] += u;
        __syncthreads();
    }
    if (t < nbins) binStart[t] = sh[t] - v;
    if (t == 0) row_start[n] = E;
}

// ---------------- phase B: per-bin CSR; stats via per-node walk of sew ----------------
__global__ __launch_bounds__(512) void k_binB(
    const int* __restrict__ binCnt, const int* __restrict__ binStart,
    const int4* __restrict__ staged, const float* __restrict__ x,
    int* __restrict__ row_start, int* __restrict__ snbr, int2* __restrict__ sew,
    half_t* __restrict__ reps, int n) {
    __shared__ int deg[NPB], cur[NPB], rsl[NPB];
    int t = threadIdx.x;
    int bin = blockIdx.x;
    int cntE = min(binCnt[bin], BIN_CAP);
    int pbase = binStart[bin];
    const int4* st = staged + (size_t)bin * BIN_CAP;

    deg[t] = 0;
    cur[t] = 0;
    __syncthreads();

    // pass 1: degree count only (1 LDS atomic/edge)
    for (int i = t; i < cntE; i += 512)
        atomicAdd(&deg[st[i].y], 1);
    __syncthreads();

    int own = deg[t];
    for (int s = 1; s < NPB; s <<= 1) {   // inclusive Hillis-Steele scan
        int u = (t >= s) ? deg[t - s] : 0;
        __syncthreads();
        deg[t] += u;
        __syncthreads();
    }
    int excl = deg[t] - own;
    rsl[t] = pbase + excl;
    int node = bin * NPB + t;
    if (node < n) row_start[node] = pbase + excl;
    __syncthreads();

    // pass 2: scatter snbr + packed ew (1 LDS atomic/edge)
    for (int i = t; i < cntE; i += 512) {
        int4 v = st[i];
        int p = rsl[v.y] + atomicAdd(&cur[v.y], 1);
        snbr[p] = v.x;
        sew[p] = make_int2(v.z, v.w);
    }
    __syncthreads();   // sew visible block-wide (same-block L2)

    // pass 3: per-node stats via sequential walk (L2-hot window, no atomics)
    if (node < n) {
        int base = rsl[t];
        float s0 = 0.f, s1 = 0.f, s2 = 0.f, s3 = 0.f;
        half2_t mxlo = {(half_t)-65504.f, (half_t)-65504.f};
        half2_t mxhi = mxlo;
        half2_t mnlo = {(half_t)65504.f, (half_t)65504.f};
        half2_t mnhi = mnlo;
#pragma unroll 2
        for (int k = 0; k < own; ++k) {
            int2 e = sew[base + k];
            half2_t lo = __builtin_bit_cast(half2_t, e.x);
            half2_t hi = __builtin_bit_cast(half2_t, e.y);
            s0 += (float)lo[0];
            s1 += (float)lo[1];
            s2 += (float)hi[0];
            s3 += (float)hi[1];
            mxlo = __builtin_elementwise_max(mxlo, lo);
            mxhi = __builtin_elementwise_max(mxhi, hi);
            mnlo = __builtin_elementwise_min(mnlo, lo);
            mnhi = __builtin_elementwise_min(mnhi, hi);
        }
        float cnt = fmaxf((float)own, 1.0f);
        float rc = __builtin_amdgcn_rcpf(cnt);
        float mx0, mx1, mx2, mx3, mn0, mn1, mn2, mn3;
        if (own == 0) {
            mx0 = mx1 = mx2 = mx3 = -FLT_MAX;
            mn0 = mn1 = mn2 = mn3 = FLT_MAX;
        } else {
            mx0 = (float)mxlo[0]; mx1 = (float)mxlo[1];
            mx2 = (float)mxhi[0]; mx3 = (float)mxhi[1];
            mn0 = (float)mnlo[0]; mn1 = (float)mnlo[1];
            mn2 = (float)mnhi[0]; mn3 = (float)mnhi[1];
        }
        const float4* x4 = reinterpret_cast<const float4*>(x);
        float4 x0 = x4[node * 2 + 0], x1 = x4[node * 2 + 1];
        half_t* o = &reps[(size_t)node * 32];
        half8 c0 = {cvt_clamp(x0.x), cvt_clamp(x0.y), cvt_clamp(x0.z), cvt_clamp(x0.w),
                    cvt_clamp(x1.x), cvt_clamp(x1.y), cvt_clamp(x1.z), cvt_clamp(x1.w)};
        half8 c1 = {cvt_clamp(s0 * rc), cvt_clamp(s1 * rc), cvt_clamp(s2 * rc), cvt_clamp(s3 * rc),
                    cvt_clamp(mx0), cvt_clamp(mx1), cvt_clamp(mx2), cvt_clamp(mx3)};
        half8 c2 = {cvt_clamp(mn0), cvt_clamp(mn1), cvt_clamp(mn2), cvt_clamp(mn3),
                    cvt_clamp(s0), cvt_clamp(s1), cvt_clamp(s2), cvt_clamp(s3)};
        half8 c3 = {(half_t)0.f, (half_t)0.f, (half_t)0.f, (half_t)0.f,
                    (half_t)0.f, (half_t)0.f, (half_t)0.f, (half_t)0.f};
        *(half8*)&o[0] = c0;
        *(half8*)&o[8] = c1;
        *(half8*)&o[16] = c2;
        *(half8*)&o[24] = c3;
    }
}

// ---------------- weight prep: fp32 [k][n] -> fp16 [n][k] ----------------
__global__ void k_wprep(const float* __restrict__ Wu1, const float* __restrict__ Wu2,
                        const float* __restrict__ Wu3, half_t* __restrict__ Wt1,
                        half_t* __restrict__ Wt2, half_t* __restrict__ Wt3) {
    int i = blockIdx.x * 256 + threadIdx.x;
    if (i < 32768) {
        int nrow = i >> 7, k = i & 127;
        Wt1[i] = (half_t)Wu1[k * 256 + nrow];
    } else if (i < 65536) {
        int j = i - 32768;
        int nrow = j >> 8, k = j & 255;
        Wt2[j] = (half_t)Wu2[k * 128 + nrow];
    } else if (i < 69632) {
        int j = i - 65536;
        int nrow = j >> 7, k = j & 127;
        Wt3[j] = (half_t)Wu3[k * 32 + nrow];
    }
}

// ---------------- fused iter: LDS-idx gather + split-K MFMA MLP + l2norm ----------------
#define MFMA16(a, b, c) __builtin_amdgcn_mfma_f32_16x16x32_f16((a), (b), (c), 0, 0, 0)

__global__ __launch_bounds__(512, 6) void k_mlp(
    const half_t* __restrict__ reps_in,
    const int* __restrict__ row_start, const int* __restrict__ snbr,
    const half_t* __restrict__ Wt1, const half_t* __restrict__ Wt2,
    const half_t* __restrict__ Wt3,
    const float* __restrict__ bu1, const float* __restrict__ bu2,
    const float* __restrict__ bu3,
    half_t* __restrict__ reps_out, int n) {
    __shared__ half_t sH[64 * 136];     // H[64][128]; later h2[64][128]
    __shared__ half_t sh1c[64 * 136];   // idx stage, then h1 chunk [64][128]
    __shared__ int sDeg[64], sPerm[64]; // degree-rank subgroup mapping
    int* sIdx = (int*)sh1c;             // 4352 int slots

    const int tid = threadIdx.x;
    const int w   = tid >> 6;
    const int l15 = tid & 15;
    const int lk  = (tid & 63) >> 4;
    const int node0 = blockIdx.x * 64;

    // ---- idx stage + per-node degrees ----
    const int nodeEnd = min(node0 + 64, n);
    const int d0blk = row_start[node0];
    const int ecnt = row_start[nodeEnd] - d0blk;
    const bool lds_ok = (ecnt <= IDXCAP);
    if (tid < 64) {
        int node = node0 + tid;
        sDeg[tid] = (node < n) ? (row_start[node + 1] - row_start[node]) : 0;
    }
    if (lds_ok) {
        for (int i = tid; i < ecnt; i += 512)
            sIdx[i] = __builtin_nontemporal_load(&snbr[d0blk + i]);
    }
    __syncthreads();
    // rank nodes by degree (desc, index tie-break) -> bijective perm
    if (tid < 64) {
        int dg = sDeg[tid];
        int rank = 0;
#pragma unroll
        for (int j = 0; j < 64; ++j) {
            int dj = sDeg[j];
            rank += (dj > dg) || (dj == dg && j < tid);
        }
        sPerm[rank] = tid;
    }
    __syncthreads();

    // ---- gather: 32 subgroups of 16 lanes; lane=(nb,ch); 16 edges/iter ----
    // subgroup -> node via degree rank: waves process degree-adjacent nodes.
    {
        const int sg = tid >> 4;
        const int l  = tid & 15;
        const int nb = l >> 2;
        const int ch = l & 3;

        for (int i = 0; i < 2; ++i) {
            int nl = sPerm[i * 32 + sg];
            int node = node0 + nl;
            float s[8];
            half2_t mx2[4], mn2[4];
#pragma unroll
            for (int f = 0; f < 8; ++f) s[f] = 0.f;
#pragma unroll
            for (int f = 0; f < 4; ++f) {
                mx2[f] = (half2_t){(half_t)-65504.f, (half_t)-65504.f};
                mn2[f] = (half2_t){(half_t)65504.f, (half_t)65504.f};
            }
            int d0 = 0, d1 = 0;
            if (node < n) { d0 = row_start[node]; d1 = row_start[node + 1]; }

            for (int e = d0; e < d1; e += 16) {
                int e0 = e + nb, e1 = e + 4 + nb, e2 = e + 8 + nb, e3 = e + 12 + nb;
                float m0 = (e0 < d1) ? 1.f : 0.f;
                float m1 = (e1 < d1) ? 1.f : 0.f;
                float m2 = (e2 < d1) ? 1.f : 0.f;
                float m3 = (e3 < d1) ? 1.f : 0.f;
                int ii0, ii1, ii2, ii3;
                if (lds_ok) {
                    ii0 = sIdx[min(e0, d1 - 1) - d0blk];
                    ii1 = sIdx[min(e1, d1 - 1) - d0blk];
                    ii2 = sIdx[min(e2, d1 - 1) - d0blk];
                    ii3 = sIdx[min(e3, d1 - 1) - d0blk];
                } else {
                    ii0 = snbr[min(e0, d1 - 1)];
                    ii1 = snbr[min(e1, d1 - 1)];
                    ii2 = snbr[min(e2, d1 - 1)];
                    ii3 = snbr[min(e3, d1 - 1)];
                }
                half8 r0 = *(const half8*)&reps_in[(size_t)ii0 * 32 + ch * 8];
                half8 r1 = *(const half8*)&reps_in[(size_t)ii1 * 32 + ch * 8];
                half8 r2 = *(const half8*)&reps_in[(size_t)ii2 * 32 + ch * 8];
                half8 r3 = *(const half8*)&reps_in[(size_t)ii3 * 32 + ch * 8];
#pragma unroll
                for (int f = 0; f < 4; ++f) {
                    half2_t a0 = (half2_t){r0[2 * f], r0[2 * f + 1]};
                    half2_t a1 = (half2_t){r1[2 * f], r1[2 * f + 1]};
                    half2_t a2 = (half2_t){r2[2 * f], r2[2 * f + 1]};
                    half2_t a3 = (half2_t){r3[2 * f], r3[2 * f + 1]};
                    mx2[f] = __builtin_elementwise_max(
                        __builtin_elementwise_max(mx2[f], a0),
                        __builtin_elementwise_max(a1,
                            __builtin_elementwise_max(a2, a3)));
                    mn2[f] = __builtin_elementwise_min(
                        __builtin_elementwise_min(mn2[f], a0),
                        __builtin_elementwise_min(a1,
                            __builtin_elementwise_min(a2, a3)));
                }
#pragma unroll
                for (int f = 0; f < 8; ++f) {
                    s[f] = fmaf((float)r0[f], m0, s[f]);
                    s[f] = fmaf((float)r1[f], m1, s[f]);
                    s[f] = fmaf((float)r2[f], m2, s[f]);
                    s[f] = fmaf((float)r3[f], m3, s[f]);
                }
            }
            // reduce across the 4 nb slots (xor strides 4, 8 inside subgroup)
#pragma unroll
            for (int f = 0; f < 8; ++f) {
                s[f] += __shfl_xor(s[f], 4);
                s[f] += __shfl_xor(s[f], 8);
            }
#pragma unroll
            for (int f = 0; f < 4; ++f) {
                mx2[f] = __builtin_elementwise_max(mx2[f], h2shfl_xor(mx2[f], 4));
                mx2[f] = __builtin_elementwise_max(mx2[f], h2shfl_xor(mx2[f], 8));
                mn2[f] = __builtin_elementwise_min(mn2[f], h2shfl_xor(mn2[f], 4));
                mn2[f] = __builtin_elementwise_min(mn2[f], h2shfl_xor(mn2[f], 8));
            }
            float cnt = fmaxf((float)(d1 - d0), 1.f);
            half8 o;
            if (nb == 0) {
                if (node < n) {
                    o = *(const half8*)&reps_in[(size_t)node * 32 + ch * 8];
                } else {
#pragma unroll
                    for (int f = 0; f < 8; ++f) o[f] = (half_t)0.f;
                }
            } else if (nb == 1) {
                float rc = __builtin_amdgcn_rcpf(cnt);
#pragma unroll
                for (int f = 0; f < 8; ++f) o[f] = cvt_clamp(s[f] * rc);
            } else if (nb == 2) {
#pragma unroll
                for (int f = 0; f < 4; ++f) {
                    o[2 * f]     = cvt_clamp((float)mx2[f][0]);
                    o[2 * f + 1] = cvt_clamp((float)mx2[f][1]);
                }
            } else {
#pragma unroll
                for (int f = 0; f < 4; ++f) {
                    o[2 * f]     = cvt_clamp((float)mn2[f][0]);
                    o[2 * f + 1] = cvt_clamp((float)mn2[f][1]);
                }
            }
            *(half8*)&sH[nl * 136 + l * 8] = o;
        }
    }
    __syncthreads();   // gather done; sIdx dead -> sh1c reusable

    // ---- split-K: 2 chunks of {GEMM1 128 cols -> GEMM2 partial} ----
    f32x4 acc2[4] = {{0.f, 0.f, 0.f, 0.f}, {0.f, 0.f, 0.f, 0.f},
                     {0.f, 0.f, 0.f, 0.f}, {0.f, 0.f, 0.f, 0.f}};
#pragma unroll
    for (int c = 0; c < 2; ++c) {
        // GEMM1 chunk c: wave w owns h1 cols [c*128 + w*16, +16)
        {
            half8 a[4];
#pragma unroll
            for (int ks = 0; ks < 4; ++ks)
                a[ks] = *(const half8*)&Wt1[(c * 128 + w * 16 + l15) * 128 + ks * 32 + lk * 8];
            f32x4 bv = *(const f32x4*)&bu1[c * 128 + w * 16 + lk * 4];
#pragma unroll
            for (int nt = 0; nt < 4; ++nt) {
                const half_t* hrow = &sH[(nt * 16 + l15) * 136 + lk * 8];
                half8 b0 = *(const half8*)&hrow[0];
                half8 b1 = *(const half8*)&hrow[32];
                half8 b2 = *(const half8*)&hrow[64];
                half8 b3 = *(const half8*)&hrow[96];
                f32x4 acc = {0.f, 0.f, 0.f, 0.f};
                acc = MFMA16(a[0], b0, acc);
                acc = MFMA16(a[1], b1, acc);
                acc = MFMA16(a[2], b2, acc);
                acc = MFMA16(a[3], b3, acc);
                half4_t o;
#pragma unroll
                for (int r = 0; r < 4; ++r)
                    o[r] = (half_t)fast_tanh(acc[r] + bv[r]);
                *(half4_t*)&sh1c[(nt * 16 + l15) * 136 + w * 16 + lk * 4] = o;
            }
        }
        __syncthreads();   // h1 chunk ready
        // GEMM2 partial: k in [c*128, c*128+128)
        {
            half8 a[4];
#pragma unroll
            for (int ks = 0; ks < 4; ++ks)
                a[ks] = *(const half8*)&Wt2[(w * 16 + l15) * 256 + c * 128 + ks * 32 + lk * 8];
#pragma unroll
            for (int nt = 0; nt < 4; ++nt) {
#pragma unroll
                for (int ks = 0; ks < 4; ++ks) {
                    half8 b = *(const half8*)&sh1c[(nt * 16 + l15) * 136 + ks * 32 + lk * 8];
                    acc2[nt] = MFMA16(a[ks], b, acc2[nt]);
                }
            }
        }
        __syncthreads();   // chunk reads done before overwrite / sH overlay
    }

    // ---- h2 = tanh(acc2 + b2) -> overlay into sH (dead after GEMM1) ----
    {
        f32x4 bv = *(const f32x4*)&bu2[w * 16 + lk * 4];
#pragma unroll
        for (int nt = 0; nt < 4; ++nt) {
            half4_t o;
#pragma unroll
            for (int r = 0; r < 4; ++r)
                o[r] = (half_t)fast_tanh(acc2[nt][r] + bv[r]);
            *(half4_t*)&sH[(nt * 16 + l15) * 136 + w * 16 + lk * 4] = o;
        }
    }
    __syncthreads();

    // ---- GEMM3 + l2norm: waves 0..3, wave w owns nodes [w*16,(w+1)*16) ----
    if (w < 4) {
        half8 a0[4], a1[4], b[4];
#pragma unroll
        for (int ks = 0; ks < 4; ++ks) {
            a0[ks] = *(const half8*)&Wt3[l15 * 128 + ks * 32 + lk * 8];
            a1[ks] = *(const half8*)&Wt3[(16 + l15) * 128 + ks * 32 + lk * 8];
            b[ks]  = *(const half8*)&sH[(w * 16 + l15) * 136 + ks * 32 + lk * 8];
        }
        f32x4 acc0 = {0.f, 0.f, 0.f, 0.f}, acc1 = {0.f, 0.f, 0.f, 0.f};
#pragma unroll
        for (int ks = 0; ks < 4; ++ks) {
            acc0 = MFMA16(a0[ks], b[ks], acc0);
            acc1 = MFMA16(a1[ks], b[ks], acc1);
        }
        f32x4 bv0 = *(const f32x4*)&bu3[lk * 4];
        f32x4 bv1 = *(const f32x4*)&bu3[16 + lk * 4];
        float v0[4], v1[4];
        float ss = 0.f;
#pragma unroll
        for (int r = 0; r < 4; ++r) {
            v0[r] = fast_tanh(acc0[r] + bv0[r]);
            v1[r] = fast_tanh(acc1[r] + bv1[r]);
            ss += v0[r] * v0[r] + v1[r] * v1[r];
        }
        ss += __shfl_xor(ss, 16);
        ss += __shfl_xor(ss, 32);
        float sc = rsqrtf(fmaxf(ss, 1e-12f));
        int node = node0 + w * 16 + l15;
        if (node < n) {
            half4_t o0, o1;
#pragma unroll
            for (int r = 0; r < 4; ++r) {
                o0[r] = (half_t)(v0[r] * sc);
                o1[r] = (half_t)(v1[r] * sc);
            }
            *(half4_t*)&reps_out[(size_t)node * 32 + lk * 4] = o0;
            *(half4_t*)&reps_out[(size_t)node * 32 + 16 + lk * 4] = o1;
        }
    }
}

// ---------------- readout: gather generators (nan->0), 32->64->32->1 ----------------
__global__ __launch_bounds__(256) void k_readout(
    const half_t* __restrict__ reps, const int* __restrict__ gen,
    const float* __restrict__ Wr1, const float* __restrict__ br1,
    const float* __restrict__ Wr2, const float* __restrict__ br2,
    const float* __restrict__ Wr3, const float* __restrict__ br3,
    float* __restrict__ out, int ngen) {
    __shared__ float sW1[32 * 64];
    __shared__ float sW2[64 * 32];
    __shared__ float sb1[64];
    __shared__ float sb2[32];
    __shared__ float sW3r[32];
    __shared__ float sb3;
    int tid = threadIdx.x;
    for (int i = tid; i < 2048; i += 256) sW1[i] = Wr1[i];
    for (int i = tid; i < 2048; i += 256) sW2[i] = Wr2[i];
    if (tid < 64) sb1[tid] = br1[tid];
    if (tid < 32) sb2[tid] = br2[tid];
    if (tid < 32) sW3r[tid] = Wr3[tid];
    if (tid == 0) sb3 = br3[0];
    __syncthreads();
    int ig = blockIdx.x * 256 + tid;
    if (ig >= ngen) return;
    int node = gen[ig];
    float g[32];
#pragma unroll
    for (int q = 0; q < 4; ++q) {
        half8 v = *(const half8*)&reps[(size_t)node * 32 + q * 8];
#pragma unroll
        for (int r = 0; r < 8; ++r) {
            float f = (float)v[r];
            g[q * 8 + r] = (f != f) ? 0.f : f;
        }
    }
    float a[64];
#pragma unroll
    for (int o = 0; o < 64; ++o) {
        float acc = sb1[o];
#pragma unroll
        for (int k = 0; k < 32; ++k) acc = fmaf(g[k], sW1[k * 64 + o], acc);
        a[o] = fast_tanh(acc);
    }
    float b[32];
#pragma unroll
    for (int o = 0; o < 32; ++o) {
        float acc = sb2[o];
#pragma unroll
        for (int k = 0; k < 64; ++k) acc = fmaf(a[k], sW2[k * 32 + o], acc);
        b[o] = fast_tanh(acc);
    }
    float acc = sb3;
#pragma unroll
    for (int k = 0; k < 32; ++k) acc = fmaf(b[k], sW3r[k], acc);
    out[ig] = acc;
}

extern "C" void kernel_launch(void* const* d_in, const int* in_sizes, int n_in,
                              void* d_out, int out_size, void* d_ws, size_t ws_size,
                              hipStream_t stream) {
    const float* x   = (const float*)d_in[0];
    const float* ew  = (const float*)d_in[1];
    const float* Wu1 = (const float*)d_in[2];
    const float* bu1 = (const float*)d_in[3];
    const float* Wu2 = (const float*)d_in[4];
    const float* bu2 = (const float*)d_in[5];
    const float* Wu3 = (const float*)d_in[6];
    const float* bu3 = (const float*)d_in[7];
    const float* Wr1 = (const float*)d_in[8];
    const float* br1 = (const float*)d_in[9];
    const float* Wr2 = (const float*)d_in[10];
    const float* br2 = (const float*)d_in[11];
    const float* Wr3 = (const float*)d_in[12];
    const float* br3 = (const float*)d_in[13];
    const int* edges = (const int*)d_in[14];
    const int* gen   = (const int*)d_in[15];

    const int n    = in_sizes[0] / 8;
    const int E    = in_sizes[1] / 4;
    const int ngen = in_sizes[15];
    const int* dst = edges;      // node_idx (segment ids)
    const int* src = edges + E;  // nbr_idx (gather source)
    float* out = (float*)d_out;

    const int nblk  = (n + 63) / 64;
    const int npad  = nblk * 64;
    const int nbins = (n + NPB - 1) / NPB;

    // workspace layout (256B aligned slabs)
    char* ws = (char*)d_ws;
    size_t off = 0;
    auto alloc = [&](size_t bytes) -> char* {
        char* p = ws + off;
        off = (off + bytes + 255) & ~(size_t)255;
        return p;
    };
    int* row_start = (int*)alloc((size_t)(n + 1) * 4);
    int* binCnt    = (int*)alloc(256 * 4);
    int* binStart  = (int*)alloc(256 * 4);
    int* snbr      = (int*)alloc((size_t)E * 4);
    int2* sew      = (int2*)alloc((size_t)E * 8);   // CSR-ordered packed fp16 ew
    half_t* repsA  = (half_t*)alloc((size_t)npad * 32 * 2);
    half_t* repsB  = (half_t*)alloc((size_t)npad * 32 * 2);
    half_t* Wt1    = (half_t*)alloc(32768 * 2);
    half_t* Wt2    = (half_t*)alloc(32768 * 2);
    half_t* Wt3    = (half_t*)alloc(4096 * 2);
    int4* staged   = (int4*)alloc((size_t)nbins * BIN_CAP * 16);   // CSR build only

    // ---- CSR build (binned) + stats + reps ----
    hipMemsetAsync(binCnt, 0, 256 * 4, stream);
    int nblkA = (E + 8191) / 8192;
    k_binA<<<nblkA, 256, 0, stream>>>(dst, src, (const float4*)ew, binCnt, staged, E, nbins);
    k_scanN<<<1, 256, 0, stream>>>(binCnt, binStart, row_start, nbins, n, E);
    k_binB<<<nbins, 512, 0, stream>>>(binCnt, binStart, staged, x,
                                      row_start, snbr, sew, repsA, n);
    k_wprep<<<272, 256, 0, stream>>>(Wu1, Wu2, Wu3, Wt1, Wt2, Wt3);

    half_t* cur = repsA;
    half_t* nxt = repsB;
    for (int it = 0; it < 3; ++it) {
        k_mlp<<<nblk, 512, 0, stream>>>(cur, row_start, snbr, Wt1, Wt2, Wt3,
                                        bu1, bu2, bu3, nxt, n);
        half_t* t = cur; cur = nxt; nxt = t;
    }

    k_readout<<<(ngen + 255) / 256, 256, 0, stream>>>(cur, gen, Wr1, br1, Wr2, br2,
                                                      Wr3, br3, out, ngen);
}

// Round 14
// 261.857 us; speedup vs baseline: 1.9068x; 1.1760x over previous
//
#include <hip/hip_runtime.h>
#include <cfloat>
#include <cmath>

// ---------------------------------------------------------------------------
// GNN message passing — fp16 MFMA, round 14.
//  R14 change (single, structural): iteration 3 computes ONLY generator
//  nodes. Dataflow: readout reads reps3[gen] only -> it3 runs k_mlp over the
//  gen list (grid 157 vs 1563). Duplicate gen entries write byte-identical
//  rows (benign race, deterministic values). it1/it2 unchanged (full sweeps;
//  it2's output feeds it3's gather of N(gen) which spans ~80% of nodes, and a
//  compacted it2 would forfeit contiguous-CSR sIdx staging — not taken).
//  k_mlp gains an optional nlist indirection; nlist path disables the sIdx
//  LDS stage (ranges non-contiguous) and guards (unsigned)node < n.
//  r13 post-mortem: degree-rank perm neutral (block critical path = max
//  degree due to barrier, not subgroup packing); kept (harmless). binB
//  sequential-walk stats confirmed (+23us total).
// MFMA mapping (verified r3-r13): D=A*B, A=W^T[nout][k], B=H[node][k]; D:
// col=lane&15=node, row=(lane>>4)*4+reg=nout.
// ---------------------------------------------------------------------------

typedef _Float16 half_t;
typedef _Float16 half8 __attribute__((ext_vector_type(8)));
typedef _Float16 half4_t __attribute__((ext_vector_type(4)));
typedef _Float16 half2_t __attribute__((ext_vector_type(2)));
typedef float f32x4 __attribute__((ext_vector_type(4)));

#define NPB 512       // nodes per bin (power of 2: bin = dst>>9)
#define BIN_CAP 9216  // slots per bin; mean 8163, sd ~90 -> +11.7 sigma
#define IDXCAP 4352   // LDS idx slots per k_mlp block (mean 1024)

__device__ __forceinline__ float fast_tanh(float x) {
    float e = __builtin_amdgcn_exp2f(x * 2.8853900817779268f);
    return 1.0f - 2.0f * __builtin_amdgcn_rcpf(1.0f + e);
}

__device__ __forceinline__ half_t cvt_clamp(float v) {
    return (half_t)fminf(fmaxf(v, -60000.f), 60000.f);
}

__device__ __forceinline__ half2_t h2shfl_xor(half2_t v, int mask) {
    int i = __builtin_bit_cast(int, v);
    i = __shfl_xor(i, mask);
    return __builtin_bit_cast(half2_t, i);
}

// ---------------- phase A: bin edges + pack fp16 ew (coalesced staging) ----------------
__global__ __launch_bounds__(256) void k_binA(
    const int* __restrict__ dst, const int* __restrict__ src,
    const float4* __restrict__ ew4,
    int* __restrict__ binCnt, int4* __restrict__ staged, int E, int nbins) {
    __shared__ int cnt[256], base[256], cur[256];
    int t = threadIdx.x;
    cnt[t] = 0;
    cur[t] = 0;
    __syncthreads();
    int e0 = blockIdx.x * 8192;
#pragma unroll 4
    for (int i = 0; i < 32; ++i) {
        int e = e0 + i * 256 + t;
        if (e < E) atomicAdd(&cnt[dst[e] >> 9], 1);
    }
    __syncthreads();
    if (t < nbins && cnt[t] > 0) base[t] = atomicAdd(&binCnt[t], cnt[t]);
    __syncthreads();
#pragma unroll 4
    for (int i = 0; i < 32; ++i) {
        int e = e0 + i * 256 + t;
        if (e < E) {
            int d = dst[e];
            int b = d >> 9;
            int j = base[b] + atomicAdd(&cur[b], 1);
            if (j < BIN_CAP) {
                float4 w = ew4[e];   // coalesced here (e sequential)
                half2_t lo = {(half_t)w.x, (half_t)w.y};
                half2_t hi = {(half_t)w.z, (half_t)w.w};
                staged[(size_t)b * BIN_CAP + j] =
                    make_int4(src[e], d & (NPB - 1),
                              __builtin_bit_cast(int, lo),
                              __builtin_bit_cast(int, hi));
            }
        }
    }
}

// ---------------- bin-count exclusive scan (nbins <= 256) ----------------
__global__ void k_scanN(const int* __restrict__ binCnt, int* __restrict__ binStart,
                        int* __restrict__ row_start, int nbins, int n, int E) {
    __shared__ int sh[256];
    int t = threadIdx.x;
    int v = (t < nbins) ? binCnt[t] : 0;
    sh[t] = v;
    __syncthreads();
    for (int s = 1; s < 256; s <<= 1) {
        int u = (t >= s) ? sh[t - s] : 0;
        __syncthreads();
        sh[t] += u;
        __syncthreads();
    }
    if (t < nbins) binStart[t] = sh[t] - v;
    if (t == 0) row_start[n] = E;
}

// ---------------- phase B: per-bin CSR; stats via per-node walk of sew ----------------
__global__ __launch_bounds__(512) void k_binB(
    const int* __restrict__ binCnt, const int* __restrict__ binStart,
    const int4* __restrict__ staged, const float* __restrict__ x,
    int* __restrict__ row_start, int* __restrict__ snbr, int2* __restrict__ sew,
    half_t* __restrict__ reps, int n) {
    __shared__ int deg[NPB], cur[NPB], rsl[NPB];
    int t = threadIdx.x;
    int bin = blockIdx.x;
    int cntE = min(binCnt[bin], BIN_CAP);
    int pbase = binStart[bin];
    const int4* st = staged + (size_t)bin * BIN_CAP;

    deg[t] = 0;
    cur[t] = 0;
    __syncthreads();

    // pass 1: degree count only (1 LDS atomic/edge)
    for (int i = t; i < cntE; i += 512)
        atomicAdd(&deg[st[i].y], 1);
    __syncthreads();

    int own = deg[t];
    for (int s = 1; s < NPB; s <<= 1) {   // inclusive Hillis-Steele scan
        int u = (t >= s) ? deg[t - s] : 0;
        __syncthreads();
        deg[t] += u;
        __syncthreads();
    }
    int excl = deg[t] - own;
    rsl[t] = pbase + excl;
    int node = bin * NPB + t;
    if (node < n) row_start[node] = pbase + excl;
    __syncthreads();

    // pass 2: scatter snbr + packed ew (1 LDS atomic/edge)
    for (int i = t; i < cntE; i += 512) {
        int4 v = st[i];
        int p = rsl[v.y] + atomicAdd(&cur[v.y], 1);
        snbr[p] = v.x;
        sew[p] = make_int2(v.z, v.w);
    }
    __syncthreads();   // sew visible block-wide (same-block L2)

    // pass 3: per-node stats via sequential walk (L2-hot window, no atomics)
    if (node < n) {
        int base = rsl[t];
        float s0 = 0.f, s1 = 0.f, s2 = 0.f, s3 = 0.f;
        half2_t mxlo = {(half_t)-65504.f, (half_t)-65504.f};
        half2_t mxhi = mxlo;
        half2_t mnlo = {(half_t)65504.f, (half_t)65504.f};
        half2_t mnhi = mnlo;
#pragma unroll 2
        for (int k = 0; k < own; ++k) {
            int2 e = sew[base + k];
            half2_t lo = __builtin_bit_cast(half2_t, e.x);
            half2_t hi = __builtin_bit_cast(half2_t, e.y);
            s0 += (float)lo[0];
            s1 += (float)lo[1];
            s2 += (float)hi[0];
            s3 += (float)hi[1];
            mxlo = __builtin_elementwise_max(mxlo, lo);
            mxhi = __builtin_elementwise_max(mxhi, hi);
            mnlo = __builtin_elementwise_min(mnlo, lo);
            mnhi = __builtin_elementwise_min(mnhi, hi);
        }
        float cnt = fmaxf((float)own, 1.0f);
        float rc = __builtin_amdgcn_rcpf(cnt);
        float mx0, mx1, mx2, mx3, mn0, mn1, mn2, mn3;
        if (own == 0) {
            mx0 = mx1 = mx2 = mx3 = -FLT_MAX;
            mn0 = mn1 = mn2 = mn3 = FLT_MAX;
        } else {
            mx0 = (float)mxlo[0]; mx1 = (float)mxlo[1];
            mx2 = (float)mxhi[0]; mx3 = (float)mxhi[1];
            mn0 = (float)mnlo[0]; mn1 = (float)mnlo[1];
            mn2 = (float)mnhi[0]; mn3 = (float)mnhi[1];
        }
        const float4* x4 = reinterpret_cast<const float4*>(x);
        float4 x0 = x4[node * 2 + 0], x1 = x4[node * 2 + 1];
        half_t* o = &reps[(size_t)node * 32];
        half8 c0 = {cvt_clamp(x0.x), cvt_clamp(x0.y), cvt_clamp(x0.z), cvt_clamp(x0.w),
                    cvt_clamp(x1.x), cvt_clamp(x1.y), cvt_clamp(x1.z), cvt_clamp(x1.w)};
        half8 c1 = {cvt_clamp(s0 * rc), cvt_clamp(s1 * rc), cvt_clamp(s2 * rc), cvt_clamp(s3 * rc),
                    cvt_clamp(mx0), cvt_clamp(mx1), cvt_clamp(mx2), cvt_clamp(mx3)};
        half8 c2 = {cvt_clamp(mn0), cvt_clamp(mn1), cvt_clamp(mn2), cvt_clamp(mn3),
                    cvt_clamp(s0), cvt_clamp(s1), cvt_clamp(s2), cvt_clamp(s3)};
        half8 c3 = {(half_t)0.f, (half_t)0.f, (half_t)0.f, (half_t)0.f,
                    (half_t)0.f, (half_t)0.f, (half_t)0.f, (half_t)0.f};
        *(half8*)&o[0] = c0;
        *(half8*)&o[8] = c1;
        *(half8*)&o[16] = c2;
        *(half8*)&o[24] = c3;
    }
}

// ---------------- weight prep: fp32 [k][n] -> fp16 [n][k] ----------------
__global__ void k_wprep(const float* __restrict__ Wu1, const float* __restrict__ Wu2,
                        const float* __restrict__ Wu3, half_t* __restrict__ Wt1,
                        half_t* __restrict__ Wt2, half_t* __restrict__ Wt3) {
    int i = blockIdx.x * 256 + threadIdx.x;
    if (i < 32768) {
        int nrow = i >> 7, k = i & 127;
        Wt1[i] = (half_t)Wu1[k * 256 + nrow];
    } else if (i < 65536) {
        int j = i - 32768;
        int nrow = j >> 8, k = j & 255;
        Wt2[j] = (half_t)Wu2[k * 128 + nrow];
    } else if (i < 69632) {
        int j = i - 65536;
        int nrow = j >> 7, k = j & 127;
        Wt3[j] = (half_t)Wu3[k * 32 + nrow];
    }
}

// ---------------- fused iter: LDS-idx gather + split-K MFMA MLP + l2norm ----------------
// nlist == nullptr: node = node0 + local slot (contiguous tile, sIdx staging).
// nlist != nullptr: node = nlist[node0 + slot] (sparse list; direct snbr reads).
#define MFMA16(a, b, c) __builtin_amdgcn_mfma_f32_16x16x32_f16((a), (b), (c), 0, 0, 0)

__global__ __launch_bounds__(512, 6) void k_mlp(
    const half_t* __restrict__ reps_in,
    const int* __restrict__ row_start, const int* __restrict__ snbr,
    const int* __restrict__ nlist, int nlen,
    const half_t* __restrict__ Wt1, const half_t* __restrict__ Wt2,
    const half_t* __restrict__ Wt3,
    const float* __restrict__ bu1, const float* __restrict__ bu2,
    const float* __restrict__ bu3,
    half_t* __restrict__ reps_out, int n) {
    __shared__ half_t sH[64 * 136];     // H[64][128]; later h2[64][128]
    __shared__ half_t sh1c[64 * 136];   // idx stage, then h1 chunk [64][128]
    __shared__ int sDeg[64], sPerm[64], sNode[64];
    int* sIdx = (int*)sh1c;             // 4352 int slots

    const int tid = threadIdx.x;
    const int w   = tid >> 6;
    const int l15 = tid & 15;
    const int lk  = (tid & 63) >> 4;
    const int node0 = blockIdx.x * 64;

    // ---- node table + degrees ----
    if (tid < 64) {
        int node;
        if (nlist) {
            int li = node0 + tid;
            node = (li < nlen) ? nlist[li] : -1;
        } else {
            node = node0 + tid;
        }
        if ((unsigned)node >= (unsigned)n) node = -1;
        sNode[tid] = node;
        sDeg[tid] = (node >= 0) ? (row_start[node + 1] - row_start[node]) : 0;
    }
    // ---- idx stage (identity path only): contiguous CSR -> coalesced burst ----
    const int nodeEnd = min(node0 + 64, n);
    int d0blk = 0;
    bool lds_ok = false;
    if (!nlist && node0 < n) {
        d0blk = row_start[node0];
        int ecnt = row_start[nodeEnd] - d0blk;
        lds_ok = (ecnt <= IDXCAP);
        if (lds_ok) {
            for (int i = tid; i < ecnt; i += 512)
                sIdx[i] = __builtin_nontemporal_load(&snbr[d0blk + i]);
        }
    }
    __syncthreads();
    // rank nodes by degree (desc, index tie-break) -> bijective perm
    if (tid < 64) {
        int dg = sDeg[tid];
        int rank = 0;
#pragma unroll
        for (int j = 0; j < 64; ++j) {
            int dj = sDeg[j];
            rank += (dj > dg) || (dj == dg && j < tid);
        }
        sPerm[rank] = tid;
    }
    __syncthreads();

    // ---- gather: 32 subgroups of 16 lanes; lane=(nb,ch); 16 edges/iter ----
    {
        const int sg = tid >> 4;
        const int l  = tid & 15;
        const int nb = l >> 2;
        const int ch = l & 3;

        for (int i = 0; i < 2; ++i) {
            int nl = sPerm[i * 32 + sg];
            int node = sNode[nl];
            float s[8];
            half2_t mx2[4], mn2[4];
#pragma unroll
            for (int f = 0; f < 8; ++f) s[f] = 0.f;
#pragma unroll
            for (int f = 0; f < 4; ++f) {
                mx2[f] = (half2_t){(half_t)-65504.f, (half_t)-65504.f};
                mn2[f] = (half2_t){(half_t)65504.f, (half_t)65504.f};
            }
            int d0 = 0, d1 = 0;
            if (node >= 0) { d0 = row_start[node]; d1 = row_start[node + 1]; }

            for (int e = d0; e < d1; e += 16) {
                int e0 = e + nb, e1 = e + 4 + nb, e2 = e + 8 + nb, e3 = e + 12 + nb;
                float m0 = (e0 < d1) ? 1.f : 0.f;
                float m1 = (e1 < d1) ? 1.f : 0.f;
                float m2 = (e2 < d1) ? 1.f : 0.f;
                float m3 = (e3 < d1) ? 1.f : 0.f;
                int ii0, ii1, ii2, ii3;
                if (lds_ok) {
                    ii0 = sIdx[min(e0, d1 - 1) - d0blk];
                    ii1 = sIdx[min(e1, d1 - 1) - d0blk];
                    ii2 = sIdx[min(e2, d1 - 1) - d0blk];
                    ii3 = sIdx[min(e3, d1 - 1) - d0blk];
                } else {
                    ii0 = snbr[min(e0, d1 - 1)];
                    ii1 = snbr[min(e1, d1 - 1)];
                    ii2 = snbr[min(e2, d1 - 1)];
                    ii3 = snbr[min(e3, d1 - 1)];
                }
                half8 r0 = *(const half8*)&reps_in[(size_t)ii0 * 32 + ch * 8];
                half8 r1 = *(const half8*)&reps_in[(size_t)ii1 * 32 + ch * 8];
                half8 r2 = *(const half8*)&reps_in[(size_t)ii2 * 32 + ch * 8];
                half8 r3 = *(const half8*)&reps_in[(size_t)ii3 * 32 + ch * 8];
#pragma unroll
                for (int f = 0; f < 4; ++f) {
                    half2_t a0 = (half2_t){r0[2 * f], r0[2 * f + 1]};
                    half2_t a1 = (half2_t){r1[2 * f], r1[2 * f + 1]};
                    half2_t a2 = (half2_t){r2[2 * f], r2[2 * f + 1]};
                    half2_t a3 = (half2_t){r3[2 * f], r3[2 * f + 1]};
                    mx2[f] = __builtin_elementwise_max(
                        __builtin_elementwise_max(mx2[f], a0),
                        __builtin_elementwise_max(a1,
                            __builtin_elementwise_max(a2, a3)));
                    mn2[f] = __builtin_elementwise_min(
                        __builtin_elementwise_min(mn2[f], a0),
                        __builtin_elementwise_min(a1,
                            __builtin_elementwise_min(a2, a3)));
                }
#pragma unroll
                for (int f = 0; f < 8; ++f) {
                    s[f] = fmaf((float)r0[f], m0, s[f]);
                    s[f] = fmaf((float)r1[f], m1, s[f]);
                    s[f] = fmaf((float)r2[f], m2, s[f]);
                    s[f] = fmaf((float)r3[f], m3, s[f]);
                }
            }
            // reduce across the 4 nb slots (xor strides 4, 8 inside subgroup)
#pragma unroll
            for (int f = 0; f < 8; ++f) {
                s[f] += __shfl_xor(s[f], 4);
                s[f] += __shfl_xor(s[f], 8);
            }
#pragma unroll
            for (int f = 0; f < 4; ++f) {
                mx2[f] = __builtin_elementwise_max(mx2[f], h2shfl_xor(mx2[f], 4));
                mx2[f] = __builtin_elementwise_max(mx2[f], h2shfl_xor(mx2[f], 8));
                mn2[f] = __builtin_elementwise_min(mn2[f], h2shfl_xor(mn2[f], 4));
                mn2[f] = __builtin_elementwise_min(mn2[f], h2shfl_xor(mn2[f], 8));
            }
            float cnt = fmaxf((float)(d1 - d0), 1.f);
            half8 o;
            if (nb == 0) {
                if (node >= 0) {
                    o = *(const half8*)&reps_in[(size_t)node * 32 + ch * 8];
                } else {
#pragma unroll
                    for (int f = 0; f < 8; ++f) o[f] = (half_t)0.f;
                }
            } else if (nb == 1) {
                float rc = __builtin_amdgcn_rcpf(cnt);
#pragma unroll
                for (int f = 0; f < 8; ++f) o[f] = cvt_clamp(s[f] * rc);
            } else if (nb == 2) {
#pragma unroll
                for (int f = 0; f < 4; ++f) {
                    o[2 * f]     = cvt_clamp((float)mx2[f][0]);
                    o[2 * f + 1] = cvt_clamp((float)mx2[f][1]);
                }
            } else {
#pragma unroll
                for (int f = 0; f < 4; ++f) {
                    o[2 * f]     = cvt_clamp((float)mn2[f][0]);
                    o[2 * f + 1] = cvt_clamp((float)mn2[f][1]);
                }
            }
            *(half8*)&sH[nl * 136 + l * 8] = o;
        }
    }
    __syncthreads();   // gather done; sIdx dead -> sh1c reusable

    // ---- split-K: 2 chunks of {GEMM1 128 cols -> GEMM2 partial} ----
    f32x4 acc2[4] = {{0.f, 0.f, 0.f, 0.f}, {0.f, 0.f, 0.f, 0.f},
                     {0.f, 0.f, 0.f, 0.f}, {0.f, 0.f, 0.f, 0.f}};
#pragma unroll
    for (int c = 0; c < 2; ++c) {
        // GEMM1 chunk c: wave w owns h1 cols [c*128 + w*16, +16)
        {
            half8 a[4];
#pragma unroll
            for (int ks = 0; ks < 4; ++ks)
                a[ks] = *(const half8*)&Wt1[(c * 128 + w * 16 + l15) * 128 + ks * 32 + lk * 8];
            f32x4 bv = *(const f32x4*)&bu1[c * 128 + w * 16 + lk * 4];
#pragma unroll
            for (int nt = 0; nt < 4; ++nt) {
                const half_t* hrow = &sH[(nt * 16 + l15) * 136 + lk * 8];
                half8 b0 = *(const half8*)&hrow[0];
                half8 b1 = *(const half8*)&hrow[32];
                half8 b2 = *(const half8*)&hrow[64];
                half8 b3 = *(const half8*)&hrow[96];
                f32x4 acc = {0.f, 0.f, 0.f, 0.f};
                acc = MFMA16(a[0], b0, acc);
                acc = MFMA16(a[1], b1, acc);
                acc = MFMA16(a[2], b2, acc);
                acc = MFMA16(a[3], b3, acc);
                half4_t o;
#pragma unroll
                for (int r = 0; r < 4; ++r)
                    o[r] = (half_t)fast_tanh(acc[r] + bv[r]);
                *(half4_t*)&sh1c[(nt * 16 + l15) * 136 + w * 16 + lk * 4] = o;
            }
        }
        __syncthreads();   // h1 chunk ready
        // GEMM2 partial: k in [c*128, c*128+128)
        {
            half8 a[4];
#pragma unroll
            for (int ks = 0; ks < 4; ++ks)
                a[ks] = *(const half8*)&Wt2[(w * 16 + l15) * 256 + c * 128 + ks * 32 + lk * 8];
#pragma unroll
            for (int nt = 0; nt < 4; ++nt) {
#pragma unroll
                for (int ks = 0; ks < 4; ++ks) {
                    half8 b = *(const half8*)&sh1c[(nt * 16 + l15) * 136 + ks * 32 + lk * 8];
                    acc2[nt] = MFMA16(a[ks], b, acc2[nt]);
                }
            }
        }
        __syncthreads();   // chunk reads done before overwrite / sH overlay
    }

    // ---- h2 = tanh(acc2 + b2) -> overlay into sH (dead after GEMM1) ----
    {
        f32x4 bv = *(const f32x4*)&bu2[w * 16 + lk * 4];
#pragma unroll
        for (int nt = 0; nt < 4; ++nt) {
            half4_t o;
#pragma unroll
            for (int r = 0; r < 4; ++r)
                o[r] = (half_t)fast_tanh(acc2[nt][r] + bv[r]);
            *(half4_t*)&sH[(nt * 16 + l15) * 136 + w * 16 + lk * 4] = o;
        }
    }
    __syncthreads();

    // ---- GEMM3 + l2norm: waves 0..3, wave w owns slots [w*16,(w+1)*16) ----
    if (w < 4) {
        half8 a0[4], a1[4], b[4];
#pragma unroll
        for (int ks = 0; ks < 4; ++ks) {
            a0[ks] = *(const half8*)&Wt3[l15 * 128 + ks * 32 + lk * 8];
            a1[ks] = *(const half8*)&Wt3[(16 + l15) * 128 + ks * 32 + lk * 8];
            b[ks]  = *(const half8*)&sH[(w * 16 + l15) * 136 + ks * 32 + lk * 8];
        }
        f32x4 acc0 = {0.f, 0.f, 0.f, 0.f}, acc1 = {0.f, 0.f, 0.f, 0.f};
#pragma unroll
        for (int ks = 0; ks < 4; ++ks) {
            acc0 = MFMA16(a0[ks], b[ks], acc0);
            acc1 = MFMA16(a1[ks], b[ks], acc1);
        }
        f32x4 bv0 = *(const f32x4*)&bu3[lk * 4];
        f32x4 bv1 = *(const f32x4*)&bu3[16 + lk * 4];
        float v0[4], v1[4];
        float ss = 0.f;
#pragma unroll
        for (int r = 0; r < 4; ++r) {
            v0[r] = fast_tanh(acc0[r] + bv0[r]);
            v1[r] = fast_tanh(acc1[r] + bv1[r]);
            ss += v0[r] * v0[r] + v1[r] * v1[r];
        }
        ss += __shfl_xor(ss, 16);
        ss += __shfl_xor(ss, 32);
        float sc = rsqrtf(fmaxf(ss, 1e-12f));
        int node = sNode[w * 16 + l15];
        if (node >= 0) {
            half4_t o0, o1;
#pragma unroll
            for (int r = 0; r < 4; ++r) {
                o0[r] = (half_t)(v0[r] * sc);
                o1[r] = (half_t)(v1[r] * sc);
            }
            *(half4_t*)&reps_out[(size_t)node * 32 + lk * 4] = o0;
            *(half4_t*)&reps_out[(size_t)node * 32 + 16 + lk * 4] = o1;
        }
    }
}

// ---------------- readout: gather generators (nan->0), 32->64->32->1 ----------------
__global__ __launch_bounds__(256) void k_readout(
    const half_t* __restrict__ reps, const int* __restrict__ gen,
    const float* __restrict__ Wr1, const float* __restrict__ br1,
    const float* __restrict__ Wr2, const float* __restrict__ br2,
    const float* __restrict__ Wr3, const float* __restrict__ br3,
    float* __restrict__ out, int ngen) {
    __shared__ float sW1[32 * 64];
    __shared__ float sW2[64 * 32];
    __shared__ float sb1[64];
    __shared__ float sb2[32];
    __shared__ float sW3r[32];
    __shared__ float sb3;
    int tid = threadIdx.x;
    for (int i = tid; i < 2048; i += 256) sW1[i] = Wr1[i];
    for (int i = tid; i < 2048; i += 256) sW2[i] = Wr2[i];
    if (tid < 64) sb1[tid] = br1[tid];
    if (tid < 32) sb2[tid] = br2[tid];
    if (tid < 32) sW3r[tid] = Wr3[tid];
    if (tid == 0) sb3 = br3[0];
    __syncthreads();
    int ig = blockIdx.x * 256 + tid;
    if (ig >= ngen) return;
    int node = gen[ig];
    float g[32];
#pragma unroll
    for (int q = 0; q < 4; ++q) {
        half8 v = *(const half8*)&reps[(size_t)node * 32 + q * 8];
#pragma unroll
        for (int r = 0; r < 8; ++r) {
            float f = (float)v[r];
            g[q * 8 + r] = (f != f) ? 0.f : f;
        }
    }
    float a[64];
#pragma unroll
    for (int o = 0; o < 64; ++o) {
        float acc = sb1[o];
#pragma unroll
        for (int k = 0; k < 32; ++k) acc = fmaf(g[k], sW1[k * 64 + o], acc);
        a[o] = fast_tanh(acc);
    }
    float b[32];
#pragma unroll
    for (int o = 0; o < 32; ++o) {
        float acc = sb2[o];
#pragma unroll
        for (int k = 0; k < 64; ++k) acc = fmaf(a[k], sW2[k * 32 + o], acc);
        b[o] = fast_tanh(acc);
    }
    float acc = sb3;
#pragma unroll
    for (int k = 0; k < 32; ++k) acc = fmaf(b[k], sW3r[k], acc);
    out[ig] = acc;
}

extern "C" void kernel_launch(void* const* d_in, const int* in_sizes, int n_in,
                              void* d_out, int out_size, void* d_ws, size_t ws_size,
                              hipStream_t stream) {
    const float* x   = (const float*)d_in[0];
    const float* ew  = (const float*)d_in[1];
    const float* Wu1 = (const float*)d_in[2];
    const float* bu1 = (const float*)d_in[3];
    const float* Wu2 = (const float*)d_in[4];
    const float* bu2 = (const float*)d_in[5];
    const float* Wu3 = (const float*)d_in[6];
    const float* bu3 = (const float*)d_in[7];
    const float* Wr1 = (const float*)d_in[8];
    const float* br1 = (const float*)d_in[9];
    const float* Wr2 = (const float*)d_in[10];
    const float* br2 = (const float*)d_in[11];
    const float* Wr3 = (const float*)d_in[12];
    const float* br3 = (const float*)d_in[13];
    const int* edges = (const int*)d_in[14];
    const int* gen   = (const int*)d_in[15];

    const int n    = in_sizes[0] / 8;
    const int E    = in_sizes[1] / 4;
    const int ngen = in_sizes[15];
    const int* dst = edges;      // node_idx (segment ids)
    const int* src = edges + E;  // nbr_idx (gather source)
    float* out = (float*)d_out;

    const int nblk  = (n + 63) / 64;
    const int npad  = nblk * 64;
    const int nbins = (n + NPB - 1) / NPB;

    // workspace layout (256B aligned slabs)
    char* ws = (char*)d_ws;
    size_t off = 0;
    auto alloc = [&](size_t bytes) -> char* {
        char* p = ws + off;
        off = (off + bytes + 255) & ~(size_t)255;
        return p;
    };
    int* row_start = (int*)alloc((size_t)(n + 1) * 4);
    int* binCnt    = (int*)alloc(256 * 4);
    int* binStart  = (int*)alloc(256 * 4);
    int* snbr      = (int*)alloc((size_t)E * 4);
    int2* sew      = (int2*)alloc((size_t)E * 8);   // CSR-ordered packed fp16 ew
    half_t* repsA  = (half_t*)alloc((size_t)npad * 32 * 2);
    half_t* repsB  = (half_t*)alloc((size_t)npad * 32 * 2);
    half_t* Wt1    = (half_t*)alloc(32768 * 2);
    half_t* Wt2    = (half_t*)alloc(32768 * 2);
    half_t* Wt3    = (half_t*)alloc(4096 * 2);
    int4* staged   = (int4*)alloc((size_t)nbins * BIN_CAP * 16);   // CSR build only

    // ---- CSR build (binned) + stats + reps ----
    hipMemsetAsync(binCnt, 0, 256 * 4, stream);
    int nblkA = (E + 8191) / 8192;
    k_binA<<<nblkA, 256, 0, stream>>>(dst, src, (const float4*)ew, binCnt, staged, E, nbins);
    k_scanN<<<1, 256, 0, stream>>>(binCnt, binStart, row_start, nbins, n, E);
    k_binB<<<nbins, 512, 0, stream>>>(binCnt, binStart, staged, x,
                                      row_start, snbr, sew, repsA, n);
    k_wprep<<<272, 256, 0, stream>>>(Wu1, Wu2, Wu3, Wt1, Wt2, Wt3);

    // it1, it2: full sweeps (identity mapping, sIdx staging)
    k_mlp<<<nblk, 512, 0, stream>>>(repsA, row_start, snbr, nullptr, 0,
                                    Wt1, Wt2, Wt3, bu1, bu2, bu3, repsB, n);
    k_mlp<<<nblk, 512, 0, stream>>>(repsB, row_start, snbr, nullptr, 0,
                                    Wt1, Wt2, Wt3, bu1, bu2, bu3, repsA, n);
    // it3: generator nodes only (readout consumes nothing else)
    int nblk3 = (ngen + 63) / 64;
    k_mlp<<<nblk3, 512, 0, stream>>>(repsA, row_start, snbr, gen, ngen,
                                     Wt1, Wt2, Wt3, bu1, bu2, bu3, repsB, n);

    k_readout<<<(ngen + 255) / 256, 256, 0, stream>>>(repsB, gen, Wr1, br1, Wr2, br2,
                                                      Wr3, br3, out, ngen);
}